// Round 7
// baseline (3389.925 us; speedup 1.0000x reference)
//
#include <hip/hip_runtime.h>
#include <hip/hip_bf16.h>

// MPNN, fp32 tensors / int32 edge_index. Round-7: edge MLPs on bf16 MFMA with
// wave-owned m-tiles (16 edges/wave, loop over 4 col-tiles) -> 4x fewer A-frag
// gathers vs r6's wave-owned col-slices. LYS 80->72 (bank-conflict fix).
// GEMM1->GEMM2 LDS round-trip is wave-private: no barriers except pre-segsum.
// BN two-pass via recompute (r6's storey path never fit ws_size; removed).
// Stats: wave partials -> LDS reduce -> 128 sharded atomics/block.

#define BN_EPS 1e-5f
#define NSH 128
#define LYS 72   // LDS y-tile row stride in shorts (mult of 8; 36 words: quads split banksets)
#define ASW 66   // node-kernel LDS stride

typedef __attribute__((ext_vector_type(8))) short short8;
typedef __attribute__((ext_vector_type(4))) float floatx4;

__device__ __forceinline__ short f2bs(float f) {
  union { float f; unsigned u; } x; x.f = f;
  unsigned r = x.u + 0x7fffu + ((x.u >> 16) & 1u);
  return (short)(r >> 16);
}
__device__ __forceinline__ float bs2f(short s) {
  union { unsigned u; float f; } x;
  x.u = ((unsigned)(unsigned short)s) << 16;
  return x.f;
}

// ---- setup kernels ---------------------------------------------------------

__global__ void lin_in_kernel(const float* __restrict__ x,
                              const float* __restrict__ W,
                              const float* __restrict__ b, float* __restrict__ h,
                              short* __restrict__ hb, int N) {
  int gid = blockIdx.x * blockDim.x + threadIdx.x;
  if (gid >= N * 64) return;
  int n = gid >> 6, o = gid & 63;
  float acc = b[o];
#pragma unroll
  for (int k = 0; k < 6; ++k) acc += x[n * 6 + k] * W[k * 64 + o];
  h[gid] = acc;
  hb[gid] = f2bs(acc);
}

__global__ void deg_kernel(const int* __restrict__ ei, int* __restrict__ deg,
                           int E) {
  int gid = blockIdx.x * blockDim.x + threadIdx.x;
  if (gid < E) atomicAdd(&deg[ei[E + gid]], 1);  // row 1 = dst
}

__global__ void scan_kernel(const int* __restrict__ deg, int* __restrict__ offs,
                            int N) {
  __shared__ int s[1024];
  int t = threadIdx.x;
  int chunk = (N + 1023) >> 10;
  int lo = t * chunk, hi = lo + chunk;
  if (hi > N) hi = N;
  if (lo > N) lo = N;
  int tot = 0;
  for (int i = lo; i < hi; ++i) tot += deg[i];
  s[t] = tot;
  __syncthreads();
  for (int off = 1; off < 1024; off <<= 1) {
    int v = (t >= off) ? s[t - off] : 0;
    __syncthreads();
    s[t] += v;
    __syncthreads();
  }
  int run = s[t] - tot;
  for (int i = lo; i < hi; ++i) {
    offs[i] = run;
    run += deg[i];
  }
}

__global__ void fill_kernel(const int* __restrict__ ei,
                            const int* __restrict__ offs, int* __restrict__ cnt,
                            int* __restrict__ sorted, int E) {
  int gid = blockIdx.x * blockDim.x + threadIdx.x;
  if (gid >= E) return;
  int d = ei[E + gid];
  int pos = offs[d] + atomicAdd(&cnt[d], 1);
  sorted[pos] = gid;
}

// pre-gather sorted dst/src/ea (padded to Epad; pad: dst=-1, src=0, ea=0)
__global__ void gather_edges_kernel(const int* __restrict__ ei,
                                    const int* __restrict__ sorted,
                                    const float* __restrict__ ea,
                                    int* __restrict__ dd, int* __restrict__ ds,
                                    short* __restrict__ es, int E, int Epad) {
  int i = blockIdx.x * 256 + threadIdx.x;
  if (i >= Epad) return;
  if (i < E) {
    int e = sorted[i];
    dd[i] = ei[E + e];
    ds[i] = ei[e];
    es[i] = f2bs(ea[e]);
  } else {
    dd[i] = -1;
    ds[i] = 0;
    es[i] = 0;
  }
}

// msg_W1 (L,129,64) -> Wt1 (L,64,160) bf16 n-major, k zero-padded
__global__ void pack_w1_kernel(const float* __restrict__ W,
                               short* __restrict__ Wt, int L_) {
  int i = blockIdx.x * 256 + threadIdx.x;
  if (i >= L_ * 64 * 160) return;
  int k = i % 160, n = (i / 160) % 64, l = i / (160 * 64);
  Wt[i] = (k < 129) ? f2bs(W[((size_t)l * 129 + k) * 64 + n]) : (short)0;
}

// msg_W2 (L,64,64) -> Wt2 (L,64,64) bf16 n-major
__global__ void pack_w2_kernel(const float* __restrict__ W,
                               short* __restrict__ Wt, int L_) {
  int i = blockIdx.x * 256 + threadIdx.x;
  if (i >= L_ * 64 * 64) return;
  int k = i % 64, n = (i / 64) % 64, l = i / 4096;
  Wt[i] = f2bs(W[((size_t)l * 64 + k) * 64 + n]);
}

// reduce NSH shards -> BN scale/shift
__global__ void bn_finalize_kernel(const float* __restrict__ shards,
                                   const float* __restrict__ gamma,
                                   const float* __restrict__ beta, float cnt,
                                   float* __restrict__ ac) {
  int o = threadIdx.x;  // 64 threads
  float s = 0.f, q = 0.f;
  for (int i = 0; i < NSH; ++i) {
    s += shards[i * 128 + o];
    q += shards[i * 128 + 64 + o];
  }
  float mu = s / cnt;
  float var = fmaxf(q / cnt - mu * mu, 0.f);
  float r = rsqrtf(var + BN_EPS);
  float g = gamma[o];
  ac[o] = g * r;
  ac[64 + o] = beta[o] - mu * g * r;
}

// ---- MFMA edge kernels -----------------------------------------------------
// Block 256 thr = 4 waves. Wave w owns edges [idx0+16w, +16) (the m-tile) and
// loops over 4 col-tiles. A-frag: A[m=lane&15][k=quad*8+j]. C: col=lane&15,
// row=quad*4+reg. Each wave's LDS rows are private -> no inter-GEMM barriers.

struct AFrags {
  short8 A0, A1, A2, A3, A4;
};

__device__ __forceinline__ AFrags load_a1(const short* __restrict__ hbf,
                                          const int* __restrict__ dd,
                                          const int* __restrict__ dsr,
                                          const short* __restrict__ es, int eg,
                                          int quad) {
  int d = dd[eg];
  d = d < 0 ? 0 : d;
  int sx = dsr[eg];
  const short* hd = hbf + (size_t)d * 64 + quad * 8;
  const short* hs = hbf + (size_t)sx * 64 + quad * 8;
  AFrags f;
  f.A0 = *(const short8*)hd;
  f.A1 = *(const short8*)(hd + 32);
  f.A2 = *(const short8*)hs;
  f.A3 = *(const short8*)(hs + 32);
  short8 z = {0, 0, 0, 0, 0, 0, 0, 0};
  if (quad == 0) z[0] = es[eg];
  f.A4 = z;
  return f;
}

__device__ __forceinline__ floatx4 gemm1_tile(const AFrags& f,
                                              const short* __restrict__ Wt1,
                                              float bias, int tn, int n16,
                                              int quad) {
  const short* wp = Wt1 + (size_t)(tn * 16 + n16) * 160 + quad * 8;
  short8 B0 = *(const short8*)wp;
  short8 B1 = *(const short8*)(wp + 32);
  short8 B2 = *(const short8*)(wp + 64);
  short8 B3 = *(const short8*)(wp + 96);
  short8 B4 = *(const short8*)(wp + 128);
  floatx4 acc = {bias, bias, bias, bias};
  acc = __builtin_amdgcn_mfma_f32_16x16x32_bf16(f.A0, B0, acc, 0, 0, 0);
  acc = __builtin_amdgcn_mfma_f32_16x16x32_bf16(f.A1, B1, acc, 0, 0, 0);
  acc = __builtin_amdgcn_mfma_f32_16x16x32_bf16(f.A2, B2, acc, 0, 0, 0);
  acc = __builtin_amdgcn_mfma_f32_16x16x32_bf16(f.A3, B3, acc, 0, 0, 0);
  acc = __builtin_amdgcn_mfma_f32_16x16x32_bf16(f.A4, B4, acc, 0, 0, 0);
  return acc;
}

// wave-level col sum/sumsq of one C tile -> sred (lanes 0..15 write)
__device__ __forceinline__ void tile_stats(floatx4 acc, int idx0, int w,
                                           int quad, int ln, int tn, int E,
                                           float* __restrict__ sredw) {
  float s = 0.f, q = 0.f;
#pragma unroll
  for (int r = 0; r < 4; ++r) {
    int el = idx0 + w * 16 + quad * 4 + r;
    float v = (el < E) ? acc[r] : 0.f;
    s += v;
    q += v * v;
  }
  s += __shfl_down(s, 32, 64);
  q += __shfl_down(q, 32, 64);
  s += __shfl_down(s, 16, 64);
  q += __shfl_down(q, 16, 64);
  if (ln < 16) {
    sredw[tn * 16 + ln] = s;
    sredw[64 + tn * 16 + ln] = q;
  }
}

__global__ __launch_bounds__(256) void edge_pass_a(
    const short* __restrict__ hbf, const short* __restrict__ Wt1,
    const float* __restrict__ b1, const int* __restrict__ dd,
    const int* __restrict__ dsr, const short* __restrict__ es,
    float* __restrict__ stat, int E) {
  __shared__ float sred[4][128];
  int t = threadIdx.x, idx0 = blockIdx.x * 64;
  int w = t >> 6, ln = t & 63, n16 = ln & 15, quad = ln >> 4;
  int eg = idx0 + w * 16 + n16;
  AFrags f = load_a1(hbf, dd, dsr, es, eg, quad);
#pragma unroll
  for (int tn = 0; tn < 4; ++tn) {
    floatx4 acc = gemm1_tile(f, Wt1, b1[tn * 16 + n16], tn, n16, quad);
    tile_stats(acc, idx0, w, quad, ln, tn, E, sred[w]);
  }
  __syncthreads();
  if (t < 128) {
    float v = sred[0][t] + sred[1][t] + sred[2][t] + sred[3][t];
    atomicAdd(&stat[(size_t)(blockIdx.x & (NSH - 1)) * 128 + t], v);
  }
}

__global__ __launch_bounds__(256) void edge_pass_b(
    const short* __restrict__ hbf, const short* __restrict__ Wt1,
    const float* __restrict__ b1, const int* __restrict__ dd,
    const int* __restrict__ dsr, const short* __restrict__ es,
    const float* __restrict__ ac1, const short* __restrict__ Wt2,
    const float* __restrict__ b2, float* __restrict__ stat, int E) {
  __shared__ __align__(16) short Ly[64 * LYS];
  __shared__ float sred[4][128];
  int t = threadIdx.x, idx0 = blockIdx.x * 64;
  int w = t >> 6, ln = t & 63, n16 = ln & 15, quad = ln >> 4;
  int eg = idx0 + w * 16 + n16;
  AFrags f = load_a1(hbf, dd, dsr, es, eg, quad);
#pragma unroll
  for (int tn = 0; tn < 4; ++tn) {
    int col = tn * 16 + n16;
    floatx4 acc = gemm1_tile(f, Wt1, b1[col], tn, n16, quad);
    float a1 = ac1[col], c1 = ac1[64 + col];
#pragma unroll
    for (int r = 0; r < 4; ++r)
      Ly[(w * 16 + quad * 4 + r) * LYS + col] =
          f2bs(fmaxf(acc[r] * a1 + c1, 0.f));
  }
  // GEMM2: wave-private rows (compiler inserts lgkm waits for LDS hazards)
  int row = w * 16 + n16;
  short8 Z0 = *(const short8*)&Ly[row * LYS + quad * 8];
  short8 Z1 = *(const short8*)&Ly[row * LYS + 32 + quad * 8];
#pragma unroll
  for (int tn = 0; tn < 4; ++tn) {
    const short* wp = Wt2 + (size_t)(tn * 16 + n16) * 64 + quad * 8;
    short8 B0 = *(const short8*)wp;
    short8 B1 = *(const short8*)(wp + 32);
    float bias = b2[tn * 16 + n16];
    floatx4 acc = {bias, bias, bias, bias};
    acc = __builtin_amdgcn_mfma_f32_16x16x32_bf16(Z0, B0, acc, 0, 0, 0);
    acc = __builtin_amdgcn_mfma_f32_16x16x32_bf16(Z1, B1, acc, 0, 0, 0);
    tile_stats(acc, idx0, w, quad, ln, tn, E, sred[w]);
  }
  __syncthreads();
  if (t < 128) {
    float v = sred[0][t] + sred[1][t] + sred[2][t] + sred[3][t];
    atomicAdd(&stat[(size_t)(blockIdx.x & (NSH - 1)) * 128 + t], v);
  }
}

__global__ __launch_bounds__(256) void edge_pass_c(
    const short* __restrict__ hbf, const short* __restrict__ Wt1,
    const float* __restrict__ b1, const int* __restrict__ dd,
    const int* __restrict__ dsr, const short* __restrict__ es,
    const float* __restrict__ ac1, const short* __restrict__ Wt2,
    const float* __restrict__ b2, const float* __restrict__ ac2,
    float* __restrict__ aggr, int E) {
  __shared__ __align__(16) short Ly[64 * LYS];
  __shared__ int sdst[64];
  int t = threadIdx.x, idx0 = blockIdx.x * 64;
  if (t < 64) sdst[t] = dd[idx0 + t];
  int w = t >> 6, ln = t & 63, n16 = ln & 15, quad = ln >> 4;
  int eg = idx0 + w * 16 + n16;
  AFrags f = load_a1(hbf, dd, dsr, es, eg, quad);
#pragma unroll
  for (int tn = 0; tn < 4; ++tn) {
    int col = tn * 16 + n16;
    floatx4 acc = gemm1_tile(f, Wt1, b1[col], tn, n16, quad);
    float a1 = ac1[col], c1 = ac1[64 + col];
#pragma unroll
    for (int r = 0; r < 4; ++r)
      Ly[(w * 16 + quad * 4 + r) * LYS + col] =
          f2bs(fmaxf(acc[r] * a1 + c1, 0.f));
  }
  int row = w * 16 + n16;
  short8 Z0 = *(const short8*)&Ly[row * LYS + quad * 8];
  short8 Z1 = *(const short8*)&Ly[row * LYS + 32 + quad * 8];
#pragma unroll
  for (int tn = 0; tn < 4; ++tn) {
    const short* wp = Wt2 + (size_t)(tn * 16 + n16) * 64 + quad * 8;
    short8 B0 = *(const short8*)wp;
    short8 B1 = *(const short8*)(wp + 32);
    float bias = b2[tn * 16 + n16];
    floatx4 acc = {bias, bias, bias, bias};
    acc = __builtin_amdgcn_mfma_f32_16x16x32_bf16(Z0, B0, acc, 0, 0, 0);
    acc = __builtin_amdgcn_mfma_f32_16x16x32_bf16(Z1, B1, acc, 0, 0, 0);
    int col2 = tn * 16 + n16;
    float a2 = ac2[col2], c2 = ac2[64 + col2];
#pragma unroll
    for (int r = 0; r < 4; ++r) {
      int el = idx0 + w * 16 + quad * 4 + r;
      float v = fmaxf(acc[r] * a2 + c2, 0.f);
      Ly[(w * 16 + quad * 4 + r) * LYS + col2] =
          f2bs((el < E) ? v : 0.f);
    }
  }
  __syncthreads();
  // segmented sum over dst-sorted runs (cross-block partials via atomics)
  int col = t & 63, g = t >> 6;
  float s = 0.f;
  int e0 = g * 16;
  for (int e = e0; e < e0 + 16; ++e) {
    int d = sdst[e];
    s += bs2f(Ly[e * LYS + col]);
    int dn = (e == e0 + 15) ? -2 : sdst[e + 1];
    if (d != dn) {
      if (d >= 0) atomicAdd(&aggr[(size_t)d * 64 + col], s);
      s = 0.f;
    }
  }
}

// ---- node pipeline (round-5 fp32 tiled, unchanged) -------------------------

__device__ __forceinline__ void gemm_r2c8(const float* __restrict__ As,
                                          const float* __restrict__ W, int K,
                                          int rg, int cg, float acc[2][8]) {
  const float* ap = As + rg * 2;
  const float* wp = W + cg * 8;
#pragma unroll 4
  for (int k = 0; k < K; ++k) {
    float2 a = *(const float2*)&ap[k * ASW];
    float4 w0 = *(const float4*)&wp[k * 64];
    float4 w1 = *(const float4*)&wp[k * 64 + 4];
    float wv[8] = {w0.x, w0.y, w0.z, w0.w, w1.x, w1.y, w1.z, w1.w};
#pragma unroll
    for (int j = 0; j < 8; ++j) {
      acc[0][j] += a.x * wv[j];
      acc[1][j] += a.y * wv[j];
    }
  }
}

__device__ __forceinline__ void stats_r2c8(const float acc[2][8],
                                           float* __restrict__ shard, int t,
                                           int cg) {
  float s[8], q[8];
#pragma unroll
  for (int j = 0; j < 8; ++j) {
    s[j] = acc[0][j] + acc[1][j];
    q[j] = acc[0][j] * acc[0][j] + acc[1][j] * acc[1][j];
  }
#pragma unroll
  for (int off = 32; off >= 8; off >>= 1) {
#pragma unroll
    for (int j = 0; j < 8; ++j) {
      s[j] += __shfl_down(s[j], off, 64);
      q[j] += __shfl_down(q[j], off, 64);
    }
  }
  if (((t & 63) >> 3) == 0) {
#pragma unroll
    for (int j = 0; j < 8; ++j) {
      atomicAdd(&shard[cg * 8 + j], s[j]);
      atomicAdd(&shard[64 + cg * 8 + j], q[j]);
    }
  }
}

__global__ __launch_bounds__(256) void node_gemm1_v3(
    const float* __restrict__ h, const float* __restrict__ aggr,
    const float* __restrict__ W, const float* __restrict__ b,
    float* __restrict__ u1, float* __restrict__ stat, int N) {
  __shared__ __align__(16) float As[128 * ASW];
  int n0 = blockIdx.x * 64;
  int t = threadIdx.x;
  int c = t & 63, g = t >> 6;
  for (int n = g; n < 64; n += 4) {
    int idx = n0 + n;
    bool v = idx < N;
    As[c * ASW + n] = v ? h[(size_t)idx * 64 + c] : 0.f;
    As[(64 + c) * ASW + n] = v ? aggr[(size_t)idx * 64 + c] : 0.f;
  }
  __syncthreads();
  int rg = t >> 3, cg = t & 7;
  float acc[2][8];
#pragma unroll
  for (int i = 0; i < 2; ++i)
#pragma unroll
    for (int j = 0; j < 8; ++j) acc[i][j] = b[cg * 8 + j];
  gemm_r2c8(As, W, 128, rg, cg, acc);
#pragma unroll
  for (int i = 0; i < 2; ++i) {
    int idx = n0 + rg * 2 + i;
    if (idx < N) {
      *(float4*)&u1[(size_t)idx * 64 + cg * 8] =
          make_float4(acc[i][0], acc[i][1], acc[i][2], acc[i][3]);
      *(float4*)&u1[(size_t)idx * 64 + cg * 8 + 4] =
          make_float4(acc[i][4], acc[i][5], acc[i][6], acc[i][7]);
    } else {
#pragma unroll
      for (int j = 0; j < 8; ++j) acc[i][j] = 0.f;
    }
  }
  stats_r2c8(acc, stat + (size_t)(blockIdx.x & (NSH - 1)) * 128, t, cg);
}

__global__ __launch_bounds__(256) void node_gemm2_v3(
    const float* __restrict__ u1, const float* __restrict__ ac,
    const float* __restrict__ W, const float* __restrict__ b,
    float* __restrict__ u2, float* __restrict__ stat, int N) {
  __shared__ __align__(16) float As[64 * ASW];
  int n0 = blockIdx.x * 64;
  int t = threadIdx.x;
  int c = t & 63, g = t >> 6;
  float a1 = ac[c], c1 = ac[64 + c];
  for (int n = g; n < 64; n += 4) {
    int idx = n0 + n;
    bool v = idx < N;
    As[c * ASW + n] = v ? fmaxf(u1[(size_t)idx * 64 + c] * a1 + c1, 0.f) : 0.f;
  }
  __syncthreads();
  int rg = t >> 3, cg = t & 7;
  float acc[2][8];
#pragma unroll
  for (int i = 0; i < 2; ++i)
#pragma unroll
    for (int j = 0; j < 8; ++j) acc[i][j] = b[cg * 8 + j];
  gemm_r2c8(As, W, 64, rg, cg, acc);
#pragma unroll
  for (int i = 0; i < 2; ++i) {
    int idx = n0 + rg * 2 + i;
    if (idx < N) {
      *(float4*)&u2[(size_t)idx * 64 + cg * 8] =
          make_float4(acc[i][0], acc[i][1], acc[i][2], acc[i][3]);
      *(float4*)&u2[(size_t)idx * 64 + cg * 8 + 4] =
          make_float4(acc[i][4], acc[i][5], acc[i][6], acc[i][7]);
    } else {
#pragma unroll
      for (int j = 0; j < 8; ++j) acc[i][j] = 0.f;
    }
  }
  stats_r2c8(acc, stat + (size_t)(blockIdx.x & (NSH - 1)) * 128, t, cg);
}

__global__ void residual_kernel(float* __restrict__ h, short* __restrict__ hb,
                                const float* __restrict__ u2,
                                const float* __restrict__ ac, int total) {
  int gid = blockIdx.x * blockDim.x + threadIdx.x;
  if (gid >= total) return;
  int o = gid & 63;
  float v = u2[gid] * ac[o] + ac[64 + o];
  float nv = h[gid] + fmaxf(v, 0.f);
  h[gid] = nv;
  hb[gid] = f2bs(nv);
}

__global__ void pred_kernel(const float* __restrict__ h,
                            const float* __restrict__ W,
                            const float* __restrict__ b,
                            float* __restrict__ out, int N) {
  int n = blockIdx.x * blockDim.x + threadIdx.x;
  if (n >= N) return;
  float acc = b[0];
  const float* hr = h + (size_t)n * 64;
#pragma unroll
  for (int o = 0; o < 64; ++o) acc += hr[o] * W[o];
  out[n] = acc;
}

// ---- launch ----------------------------------------------------------------

extern "C" void kernel_launch(void* const* d_in, const int* in_sizes, int n_in,
                              void* d_out, int out_size, void* d_ws,
                              size_t ws_size, hipStream_t stream) {
  const float* x = (const float*)d_in[0];
  const int* ei = (const int*)d_in[1];
  const float* ea = (const float*)d_in[2];
  const float* lin_W = (const float*)d_in[3];
  const float* lin_b = (const float*)d_in[4];
  const float* msg_W1 = (const float*)d_in[5];
  const float* msg_b1 = (const float*)d_in[6];
  const float* msg_g1 = (const float*)d_in[7];
  const float* msg_be1 = (const float*)d_in[8];
  const float* msg_W2 = (const float*)d_in[9];
  const float* msg_b2 = (const float*)d_in[10];
  const float* msg_g2 = (const float*)d_in[11];
  const float* msg_be2 = (const float*)d_in[12];
  const float* upd_W1 = (const float*)d_in[13];
  const float* upd_b1 = (const float*)d_in[14];
  const float* upd_g1 = (const float*)d_in[15];
  const float* upd_be1 = (const float*)d_in[16];
  const float* upd_W2 = (const float*)d_in[17];
  const float* upd_b2 = (const float*)d_in[18];
  const float* upd_g2 = (const float*)d_in[19];
  const float* upd_be2 = (const float*)d_in[20];
  const float* pred_W = (const float*)d_in[21];
  const float* pred_b = (const float*)d_in[22];
  float* out = (float*)d_out;

  const int N = in_sizes[0] / 6;
  const int E = in_sizes[1] / 2;
  const int L = 4;
  const int Epad = ((E + 63) / 64) * 64;

  char* p = (char*)d_ws;
  auto alloc = [&](size_t bytes) {
    void* r = (void*)p;
    p += (bytes + 255) & ~(size_t)255;
    return r;
  };
  float* h = (float*)alloc((size_t)N * 64 * 4);
  short* hb = (short*)alloc((size_t)N * 64 * 2);
  float* aggr = (float*)alloc((size_t)N * 64 * 4);
  float* u1 = (float*)alloc((size_t)N * 64 * 4);
  float* u2 = (float*)alloc((size_t)N * 64 * 4);
  float* stats = (float*)alloc((size_t)4 * NSH * 128 * 4);
  float* ac1 = (float*)alloc(128 * 4);
  float* ac2 = (float*)alloc(128 * 4);
  float* acu1 = (float*)alloc(128 * 4);
  float* acu2 = (float*)alloc(128 * 4);
  int* deg = (int*)alloc((size_t)N * 4);
  int* offs = (int*)alloc((size_t)N * 4);
  int* cnt = (int*)alloc((size_t)N * 4);
  int* sorted = (int*)alloc((size_t)E * 4);
  int* dd = (int*)alloc((size_t)Epad * 4);
  int* dsr = (int*)alloc((size_t)Epad * 4);
  short* es = (short*)alloc((size_t)Epad * 2);
  short* Wt1 = (short*)alloc((size_t)L * 64 * 160 * 2);
  short* Wt2 = (short*)alloc((size_t)L * 64 * 64 * 2);

  const int B = 256;
  const size_t REG = (size_t)NSH * 128;
  int gridE256 = (E + 255) / 256;
  int gridEb = Epad / 64;
  int gridM64 = (N + 63) / 64;
  int gridN64 = (N * 64 + B - 1) / B;
  int gridN = (N + B - 1) / B;

  // setup
  hipMemsetAsync(deg, 0, (size_t)N * 4, stream);
  hipMemsetAsync(cnt, 0, (size_t)N * 4, stream);
  lin_in_kernel<<<gridN64, B, 0, stream>>>(x, lin_W, lin_b, h, hb, N);
  deg_kernel<<<gridE256, B, 0, stream>>>(ei, deg, E);
  scan_kernel<<<1, 1024, 0, stream>>>(deg, offs, N);
  fill_kernel<<<gridE256, B, 0, stream>>>(ei, offs, cnt, sorted, E);
  gather_edges_kernel<<<(Epad + 255) / 256, B, 0, stream>>>(ei, sorted, ea, dd,
                                                            dsr, es, E, Epad);
  pack_w1_kernel<<<(L * 64 * 160 + 255) / 256, B, 0, stream>>>(msg_W1, Wt1, L);
  pack_w2_kernel<<<(L * 64 * 64 + 255) / 256, B, 0, stream>>>(msg_W2, Wt2, L);

  for (int l = 0; l < L; ++l) {
    const short* Wt1l = Wt1 + (size_t)l * 64 * 160;
    const short* Wt2l = Wt2 + (size_t)l * 64 * 64;
    const float* U1 = upd_W1 + (size_t)l * 128 * 64;
    const float* U2 = upd_W2 + (size_t)l * 64 * 64;
    hipMemsetAsync(stats, 0, (size_t)4 * REG * 4, stream);
    hipMemsetAsync(aggr, 0, (size_t)N * 64 * 4, stream);
    edge_pass_a<<<gridEb, 256, 0, stream>>>(hb, Wt1l, msg_b1 + l * 64, dd, dsr,
                                            es, stats, E);
    bn_finalize_kernel<<<1, 64, 0, stream>>>(stats, msg_g1 + l * 64,
                                             msg_be1 + l * 64, (float)E, ac1);
    edge_pass_b<<<gridEb, 256, 0, stream>>>(hb, Wt1l, msg_b1 + l * 64, dd, dsr,
                                            es, ac1, Wt2l, msg_b2 + l * 64,
                                            stats + REG, E);
    bn_finalize_kernel<<<1, 64, 0, stream>>>(stats + REG, msg_g2 + l * 64,
                                             msg_be2 + l * 64, (float)E, ac2);
    edge_pass_c<<<gridEb, 256, 0, stream>>>(hb, Wt1l, msg_b1 + l * 64, dd, dsr,
                                            es, ac1, Wt2l, msg_b2 + l * 64, ac2,
                                            aggr, E);
    node_gemm1_v3<<<gridM64, 256, 0, stream>>>(h, aggr, U1, upd_b1 + l * 64,
                                               u1, stats + 2 * REG, N);
    bn_finalize_kernel<<<1, 64, 0, stream>>>(stats + 2 * REG, upd_g1 + l * 64,
                                             upd_be1 + l * 64, (float)N, acu1);
    node_gemm2_v3<<<gridM64, 256, 0, stream>>>(u1, acu1, U2, upd_b2 + l * 64,
                                               u2, stats + 3 * REG, N);
    bn_finalize_kernel<<<1, 64, 0, stream>>>(stats + 3 * REG, upd_g2 + l * 64,
                                             upd_be2 + l * 64, (float)N, acu2);
    residual_kernel<<<gridN64, B, 0, stream>>>(h, hb, u2, acu2, N * 64);
  }
  pred_kernel<<<gridN, B, 0, stream>>>(h, pred_W, pred_b, out, N);
}

// Round 8
// 2555.090 us; speedup vs baseline: 1.3267x; 1.3267x over previous
//
#include <hip/hip_runtime.h>
#include <hip/hip_bf16.h>

// MPNN, fp32 tensors / int32 edge_index. Round-8: revert to r6 decomposition
// (wave owns 16-col slice, B-frags in regs once — r7's m-tile ownership
// regressed via 20 extra B VMEM loads/thread). 128 edges/block (8 m-tiles).
// BN1/BN2 folded into per-layer repacked weights (a*W, a*b+c) -> no BN FMAs in
// hot kernels. Stats: register-accumulated across m-tiles, one shuffle-reduce,
// sharded atomics (NSH=128). LYS=72 (r7 bank fix, conflicts 6.4M->0.8M).
// Cheap round-half-up for bf16 LDS intermediates.

#define BN_EPS 1e-5f
#define NSH 128
#define LYS 72   // LDS y-tile row stride in shorts (144B rows, 16B-aligned)
#define ASW 66   // node-kernel LDS stride

typedef __attribute__((ext_vector_type(8))) short short8;
typedef __attribute__((ext_vector_type(4))) float floatx4;

__device__ __forceinline__ short f2bs(float f) {  // RNE (weights, h)
  union { float f; unsigned u; } x; x.f = f;
  unsigned r = x.u + 0x7fffu + ((x.u >> 16) & 1u);
  return (short)(r >> 16);
}
__device__ __forceinline__ short f2bs_fast(float f) {  // round-half-up (LDS)
  union { float f; unsigned u; } x; x.f = f;
  return (short)((x.u + 0x8000u) >> 16);
}
__device__ __forceinline__ float bs2f(short s) {
  union { unsigned u; float f; } x;
  x.u = ((unsigned)(unsigned short)s) << 16;
  return x.f;
}

// ---- setup kernels ---------------------------------------------------------

__global__ void lin_in_kernel(const float* __restrict__ x,
                              const float* __restrict__ W,
                              const float* __restrict__ b, float* __restrict__ h,
                              short* __restrict__ hb, int N) {
  int gid = blockIdx.x * blockDim.x + threadIdx.x;
  if (gid >= N * 64) return;
  int n = gid >> 6, o = gid & 63;
  float acc = b[o];
#pragma unroll
  for (int k = 0; k < 6; ++k) acc += x[n * 6 + k] * W[k * 64 + o];
  h[gid] = acc;
  hb[gid] = f2bs(acc);
}

__global__ void deg_kernel(const int* __restrict__ ei, int* __restrict__ deg,
                           int E) {
  int gid = blockIdx.x * blockDim.x + threadIdx.x;
  if (gid < E) atomicAdd(&deg[ei[E + gid]], 1);  // row 1 = dst
}

__global__ void scan_kernel(const int* __restrict__ deg, int* __restrict__ offs,
                            int N) {
  __shared__ int s[1024];
  int t = threadIdx.x;
  int chunk = (N + 1023) >> 10;
  int lo = t * chunk, hi = lo + chunk;
  if (hi > N) hi = N;
  if (lo > N) lo = N;
  int tot = 0;
  for (int i = lo; i < hi; ++i) tot += deg[i];
  s[t] = tot;
  __syncthreads();
  for (int off = 1; off < 1024; off <<= 1) {
    int v = (t >= off) ? s[t - off] : 0;
    __syncthreads();
    s[t] += v;
    __syncthreads();
  }
  int run = s[t] - tot;
  for (int i = lo; i < hi; ++i) {
    offs[i] = run;
    run += deg[i];
  }
}

__global__ void fill_kernel(const int* __restrict__ ei,
                            const int* __restrict__ offs, int* __restrict__ cnt,
                            int* __restrict__ sorted, int E) {
  int gid = blockIdx.x * blockDim.x + threadIdx.x;
  if (gid >= E) return;
  int d = ei[E + gid];
  int pos = offs[d] + atomicAdd(&cnt[d], 1);
  sorted[pos] = gid;
}

// pre-gather sorted dst/src/ea (padded to Epad; pad: dst=-1, src=0, ea=0)
__global__ void gather_edges_kernel(const int* __restrict__ ei,
                                    const int* __restrict__ sorted,
                                    const float* __restrict__ ea,
                                    int* __restrict__ dd, int* __restrict__ ds,
                                    short* __restrict__ es, int E, int Epad) {
  int i = blockIdx.x * 256 + threadIdx.x;
  if (i >= Epad) return;
  if (i < E) {
    int e = sorted[i];
    dd[i] = ei[E + e];
    ds[i] = ei[e];
    es[i] = f2bs(ea[e]);
  } else {
    dd[i] = -1;
    ds[i] = 0;
    es[i] = 0;
  }
}

// msg_W1 (L,129,64) -> Wt1 (L,64,160) bf16 n-major, k zero-padded (plain)
__global__ void pack_w1_kernel(const float* __restrict__ W,
                               short* __restrict__ Wt, int L_) {
  int i = blockIdx.x * 256 + threadIdx.x;
  if (i >= L_ * 64 * 160) return;
  int k = i % 160, n = (i / 160) % 64, l = i / (160 * 64);
  Wt[i] = (k < 129) ? f2bs(W[((size_t)l * 129 + k) * 64 + n]) : (short)0;
}

// msg_W2 (L,64,64) -> Wt2 (L,64,64) bf16 n-major (plain)
__global__ void pack_w2_kernel(const float* __restrict__ W,
                               short* __restrict__ Wt, int L_) {
  int i = blockIdx.x * 256 + threadIdx.x;
  if (i >= L_ * 64 * 64) return;
  int k = i % 64, n = (i / 64) % 64, l = i / 4096;
  Wt[i] = f2bs(W[((size_t)l * 64 + k) * 64 + n]);
}

// BN-folded repacks (per layer, after bn_finalize): Wt[n][k] = a[n]*W[k][n],
// bs[n] = a[n]*b[n] + c[n]
__global__ void pack_w1s_kernel(const float* __restrict__ W,  // 129x64 layer
                                const float* __restrict__ b,
                                const float* __restrict__ ac,
                                short* __restrict__ Wt, float* __restrict__ bs) {
  int i = blockIdx.x * 256 + threadIdx.x;
  if (i >= 64 * 160) return;
  int k = i % 160, n = i / 160;
  Wt[i] = (k < 129) ? f2bs(W[k * 64 + n] * ac[n]) : (short)0;
  if (i < 64) bs[i] = ac[i] * b[i] + ac[64 + i];
}

__global__ void pack_w2s_kernel(const float* __restrict__ W,  // 64x64 layer
                                const float* __restrict__ b,
                                const float* __restrict__ ac,
                                short* __restrict__ Wt, float* __restrict__ bs) {
  int i = blockIdx.x * 256 + threadIdx.x;
  if (i >= 64 * 64) return;
  int k = i % 64, n = i / 64;
  Wt[i] = f2bs(W[k * 64 + n] * ac[n]);
  if (i < 64) bs[i] = ac[i] * b[i] + ac[64 + i];
}

// reduce NSH shards -> BN scale/shift
__global__ void bn_finalize_kernel(const float* __restrict__ shards,
                                   const float* __restrict__ gamma,
                                   const float* __restrict__ beta, float cnt,
                                   float* __restrict__ ac) {
  int o = threadIdx.x;  // 64 threads
  float s = 0.f, q = 0.f;
  for (int i = 0; i < NSH; ++i) {
    s += shards[i * 128 + o];
    q += shards[i * 128 + 64 + o];
  }
  float mu = s / cnt;
  float var = fmaxf(q / cnt - mu * mu, 0.f);
  float r = rsqrtf(var + BN_EPS);
  float g = gamma[o];
  ac[o] = g * r;
  ac[64 + o] = beta[o] - mu * g * r;
}

// ---- MFMA edge kernels -----------------------------------------------------
// Block 256 thr = 4 waves; wave w owns output cols [16w,16w+16), B-frags in
// registers once. 128 edges/block = 8 m-tiles. A-frag: m=lane&15, k=quad*8+j.
// C: col=lane&15, row=quad*4+reg.

#define MFMA_BF16 __builtin_amdgcn_mfma_f32_16x16x32_bf16

__global__ __launch_bounds__(256) void edge_pass_a(
    const short* __restrict__ hbf, const short* __restrict__ Wt1,
    const float* __restrict__ b1, const int* __restrict__ dd,
    const int* __restrict__ dsr, const short* __restrict__ es,
    float* __restrict__ stat, int E) {
  __shared__ int sdst[128], ssrc[128];
  __shared__ short sea[128];
  int t = threadIdx.x, idx0 = blockIdx.x * 128;
  if (t < 128) {
    sdst[t] = dd[idx0 + t];
    ssrc[t] = dsr[idx0 + t];
    sea[t] = es[idx0 + t];
  }
  __syncthreads();
  int w = t >> 6, ln = t & 63, n16 = ln & 15, quad = ln >> 4;
  int col = w * 16 + n16;
  const short* wp = Wt1 + (size_t)col * 160 + quad * 8;
  short8 B0 = *(const short8*)wp;
  short8 B1 = *(const short8*)(wp + 32);
  short8 B2 = *(const short8*)(wp + 64);
  short8 B3 = *(const short8*)(wp + 96);
  short8 B4 = *(const short8*)(wp + 128);
  float bias = b1[col];
  bool full = (idx0 + 128 <= E);
  float s = 0.f, q = 0.f;
#pragma unroll
  for (int tm = 0; tm < 8; ++tm) {
    int m = tm * 16 + n16;
    int d = sdst[m];
    d = d < 0 ? 0 : d;
    int sx = ssrc[m];
    const short* hd = hbf + (size_t)d * 64 + quad * 8;
    const short* hs = hbf + (size_t)sx * 64 + quad * 8;
    short8 a0 = *(const short8*)hd;
    short8 a1 = *(const short8*)(hd + 32);
    short8 a2 = *(const short8*)hs;
    short8 a3 = *(const short8*)(hs + 32);
    short8 a4 = {0, 0, 0, 0, 0, 0, 0, 0};
    if (quad == 0) a4[0] = sea[m];
    floatx4 acc = {bias, bias, bias, bias};
    acc = MFMA_BF16(a0, B0, acc, 0, 0, 0);
    acc = MFMA_BF16(a1, B1, acc, 0, 0, 0);
    acc = MFMA_BF16(a2, B2, acc, 0, 0, 0);
    acc = MFMA_BF16(a3, B3, acc, 0, 0, 0);
    acc = MFMA_BF16(a4, B4, acc, 0, 0, 0);
#pragma unroll
    for (int r = 0; r < 4; ++r) {
      float v = acc[r];
      if (!full && idx0 + tm * 16 + quad * 4 + r >= E) v = 0.f;
      s += v;
      q += v * v;
    }
  }
  s += __shfl_down(s, 32, 64);
  q += __shfl_down(q, 32, 64);
  s += __shfl_down(s, 16, 64);
  q += __shfl_down(q, 16, 64);
  if (ln < 16) {
    float* shard = stat + (size_t)(blockIdx.x & (NSH - 1)) * 128;
    atomicAdd(&shard[col], s);
    atomicAdd(&shard[64 + col], q);
  }
}

__global__ __launch_bounds__(256) void edge_pass_b(
    const short* __restrict__ hbf, const short* __restrict__ Wt1s,
    const float* __restrict__ b1s, const int* __restrict__ dd,
    const int* __restrict__ dsr, const short* __restrict__ es,
    const short* __restrict__ Wt2, const float* __restrict__ b2,
    float* __restrict__ stat, int E) {
  __shared__ int sdst[128], ssrc[128];
  __shared__ short sea[128];
  __shared__ __align__(16) short Ly[128 * LYS];
  int t = threadIdx.x, idx0 = blockIdx.x * 128;
  if (t < 128) {
    sdst[t] = dd[idx0 + t];
    ssrc[t] = dsr[idx0 + t];
    sea[t] = es[idx0 + t];
  }
  __syncthreads();
  int w = t >> 6, ln = t & 63, n16 = ln & 15, quad = ln >> 4;
  int col = w * 16 + n16;
  const short* wp = Wt1s + (size_t)col * 160 + quad * 8;
  short8 B0 = *(const short8*)wp;
  short8 B1 = *(const short8*)(wp + 32);
  short8 B2 = *(const short8*)(wp + 64);
  short8 B3 = *(const short8*)(wp + 96);
  short8 B4 = *(const short8*)(wp + 128);
  float bias1 = b1s[col];
#pragma unroll
  for (int tm = 0; tm < 8; ++tm) {
    int m = tm * 16 + n16;
    int d = sdst[m];
    d = d < 0 ? 0 : d;
    int sx = ssrc[m];
    const short* hd = hbf + (size_t)d * 64 + quad * 8;
    const short* hs = hbf + (size_t)sx * 64 + quad * 8;
    short8 a0 = *(const short8*)hd;
    short8 a1 = *(const short8*)(hd + 32);
    short8 a2 = *(const short8*)hs;
    short8 a3 = *(const short8*)(hs + 32);
    short8 a4 = {0, 0, 0, 0, 0, 0, 0, 0};
    if (quad == 0) a4[0] = sea[m];
    floatx4 acc = {bias1, bias1, bias1, bias1};
    acc = MFMA_BF16(a0, B0, acc, 0, 0, 0);
    acc = MFMA_BF16(a1, B1, acc, 0, 0, 0);
    acc = MFMA_BF16(a2, B2, acc, 0, 0, 0);
    acc = MFMA_BF16(a3, B3, acc, 0, 0, 0);
    acc = MFMA_BF16(a4, B4, acc, 0, 0, 0);
#pragma unroll
    for (int r = 0; r < 4; ++r)
      Ly[(tm * 16 + quad * 4 + r) * LYS + col] =
          f2bs_fast(fmaxf(acc[r], 0.f));
  }
  __syncthreads();
  const short* wp2 = Wt2 + (size_t)col * 64 + quad * 8;
  short8 C0 = *(const short8*)wp2;
  short8 C1 = *(const short8*)(wp2 + 32);
  float bias2 = b2[col];
  bool full = (idx0 + 128 <= E);
  float s = 0.f, q = 0.f;
#pragma unroll
  for (int tm = 0; tm < 8; ++tm) {
    int row = tm * 16 + n16;
    short8 Z0 = *(const short8*)&Ly[row * LYS + quad * 8];
    short8 Z1 = *(const short8*)&Ly[row * LYS + 32 + quad * 8];
    floatx4 acc = {bias2, bias2, bias2, bias2};
    acc = MFMA_BF16(Z0, C0, acc, 0, 0, 0);
    acc = MFMA_BF16(Z1, C1, acc, 0, 0, 0);
#pragma unroll
    for (int r = 0; r < 4; ++r) {
      float v = acc[r];
      if (!full && idx0 + tm * 16 + quad * 4 + r >= E) v = 0.f;
      s += v;
      q += v * v;
    }
  }
  s += __shfl_down(s, 32, 64);
  q += __shfl_down(q, 32, 64);
  s += __shfl_down(s, 16, 64);
  q += __shfl_down(q, 16, 64);
  if (ln < 16) {
    float* shard = stat + (size_t)(blockIdx.x & (NSH - 1)) * 128;
    atomicAdd(&shard[col], s);
    atomicAdd(&shard[64 + col], q);
  }
}

__global__ __launch_bounds__(256) void edge_pass_c(
    const short* __restrict__ hbf, const short* __restrict__ Wt1s,
    const float* __restrict__ b1s, const int* __restrict__ dd,
    const int* __restrict__ dsr, const short* __restrict__ es,
    const short* __restrict__ Wt2s, const float* __restrict__ b2s,
    float* __restrict__ aggr, int E) {
  __shared__ int sdst[128], ssrc[128];
  __shared__ short sea[128];
  __shared__ __align__(16) short Ly[128 * LYS];
  int t = threadIdx.x, idx0 = blockIdx.x * 128;
  if (t < 128) {
    sdst[t] = dd[idx0 + t];
    ssrc[t] = dsr[idx0 + t];
    sea[t] = es[idx0 + t];
  }
  __syncthreads();
  int w = t >> 6, ln = t & 63, n16 = ln & 15, quad = ln >> 4;
  int col = w * 16 + n16;
  const short* wp = Wt1s + (size_t)col * 160 + quad * 8;
  short8 B0 = *(const short8*)wp;
  short8 B1 = *(const short8*)(wp + 32);
  short8 B2 = *(const short8*)(wp + 64);
  short8 B3 = *(const short8*)(wp + 96);
  short8 B4 = *(const short8*)(wp + 128);
  float bias1 = b1s[col];
#pragma unroll
  for (int tm = 0; tm < 8; ++tm) {
    int m = tm * 16 + n16;
    int d = sdst[m];
    d = d < 0 ? 0 : d;
    int sx = ssrc[m];
    const short* hd = hbf + (size_t)d * 64 + quad * 8;
    const short* hs = hbf + (size_t)sx * 64 + quad * 8;
    short8 a0 = *(const short8*)hd;
    short8 a1 = *(const short8*)(hd + 32);
    short8 a2 = *(const short8*)hs;
    short8 a3 = *(const short8*)(hs + 32);
    short8 a4 = {0, 0, 0, 0, 0, 0, 0, 0};
    if (quad == 0) a4[0] = sea[m];
    floatx4 acc = {bias1, bias1, bias1, bias1};
    acc = MFMA_BF16(a0, B0, acc, 0, 0, 0);
    acc = MFMA_BF16(a1, B1, acc, 0, 0, 0);
    acc = MFMA_BF16(a2, B2, acc, 0, 0, 0);
    acc = MFMA_BF16(a3, B3, acc, 0, 0, 0);
    acc = MFMA_BF16(a4, B4, acc, 0, 0, 0);
#pragma unroll
    for (int r = 0; r < 4; ++r)
      Ly[(tm * 16 + quad * 4 + r) * LYS + col] =
          f2bs_fast(fmaxf(acc[r], 0.f));
  }
  __syncthreads();
  const short* wp2 = Wt2s + (size_t)col * 64 + quad * 8;
  short8 C0 = *(const short8*)wp2;
  short8 C1 = *(const short8*)(wp2 + 32);
  float bias2 = b2s[col];
  float y2v[8][4];
#pragma unroll
  for (int tm = 0; tm < 8; ++tm) {
    int row = tm * 16 + n16;
    short8 Z0 = *(const short8*)&Ly[row * LYS + quad * 8];
    short8 Z1 = *(const short8*)&Ly[row * LYS + 32 + quad * 8];
    floatx4 acc = {bias2, bias2, bias2, bias2};
    acc = MFMA_BF16(Z0, C0, acc, 0, 0, 0);
    acc = MFMA_BF16(Z1, C1, acc, 0, 0, 0);
#pragma unroll
    for (int r = 0; r < 4; ++r) y2v[tm][r] = fmaxf(acc[r], 0.f);
  }
  __syncthreads();  // all z reads complete before overwrite
#pragma unroll
  for (int tm = 0; tm < 8; ++tm)
#pragma unroll
    for (int r = 0; r < 4; ++r)
      Ly[(tm * 16 + quad * 4 + r) * LYS + col] = f2bs_fast(y2v[tm][r]);
  __syncthreads();
  // segmented sum over dst-sorted runs (cross-block partials via atomics);
  // padded edges (dst=-1) never flush.
  int scol = t & 63, g = t >> 6;
  float sacc = 0.f;
  int e0 = g * 32;
  for (int e = e0; e < e0 + 32; ++e) {
    int d2 = sdst[e];
    sacc += bs2f(Ly[e * LYS + scol]);
    int dn = (e == e0 + 31) ? -2 : sdst[e + 1];
    if (d2 != dn) {
      if (d2 >= 0) atomicAdd(&aggr[(size_t)d2 * 64 + scol], sacc);
      sacc = 0.f;
    }
  }
}

// ---- node pipeline (round-5 fp32 tiled, unchanged) -------------------------

__device__ __forceinline__ void gemm_r2c8(const float* __restrict__ As,
                                          const float* __restrict__ W, int K,
                                          int rg, int cg, float acc[2][8]) {
  const float* ap = As + rg * 2;
  const float* wp = W + cg * 8;
#pragma unroll 4
  for (int k = 0; k < K; ++k) {
    float2 a = *(const float2*)&ap[k * ASW];
    float4 w0 = *(const float4*)&wp[k * 64];
    float4 w1 = *(const float4*)&wp[k * 64 + 4];
    float wv[8] = {w0.x, w0.y, w0.z, w0.w, w1.x, w1.y, w1.z, w1.w};
#pragma unroll
    for (int j = 0; j < 8; ++j) {
      acc[0][j] += a.x * wv[j];
      acc[1][j] += a.y * wv[j];
    }
  }
}

__device__ __forceinline__ void stats_r2c8(const float acc[2][8],
                                           float* __restrict__ shard, int t,
                                           int cg) {
  float s[8], q[8];
#pragma unroll
  for (int j = 0; j < 8; ++j) {
    s[j] = acc[0][j] + acc[1][j];
    q[j] = acc[0][j] * acc[0][j] + acc[1][j] * acc[1][j];
  }
#pragma unroll
  for (int off = 32; off >= 8; off >>= 1) {
#pragma unroll
    for (int j = 0; j < 8; ++j) {
      s[j] += __shfl_down(s[j], off, 64);
      q[j] += __shfl_down(q[j], off, 64);
    }
  }
  if (((t & 63) >> 3) == 0) {
#pragma unroll
    for (int j = 0; j < 8; ++j) {
      atomicAdd(&shard[cg * 8 + j], s[j]);
      atomicAdd(&shard[64 + cg * 8 + j], q[j]);
    }
  }
}

__global__ __launch_bounds__(256) void node_gemm1_v3(
    const float* __restrict__ h, const float* __restrict__ aggr,
    const float* __restrict__ W, const float* __restrict__ b,
    float* __restrict__ u1, float* __restrict__ stat, int N) {
  __shared__ __align__(16) float As[128 * ASW];
  int n0 = blockIdx.x * 64;
  int t = threadIdx.x;
  int c = t & 63, g = t >> 6;
  for (int n = g; n < 64; n += 4) {
    int idx = n0 + n;
    bool v = idx < N;
    As[c * ASW + n] = v ? h[(size_t)idx * 64 + c] : 0.f;
    As[(64 + c) * ASW + n] = v ? aggr[(size_t)idx * 64 + c] : 0.f;
  }
  __syncthreads();
  int rg = t >> 3, cg = t & 7;
  float acc[2][8];
#pragma unroll
  for (int i = 0; i < 2; ++i)
#pragma unroll
    for (int j = 0; j < 8; ++j) acc[i][j] = b[cg * 8 + j];
  gemm_r2c8(As, W, 128, rg, cg, acc);
#pragma unroll
  for (int i = 0; i < 2; ++i) {
    int idx = n0 + rg * 2 + i;
    if (idx < N) {
      *(float4*)&u1[(size_t)idx * 64 + cg * 8] =
          make_float4(acc[i][0], acc[i][1], acc[i][2], acc[i][3]);
      *(float4*)&u1[(size_t)idx * 64 + cg * 8 + 4] =
          make_float4(acc[i][4], acc[i][5], acc[i][6], acc[i][7]);
    } else {
#pragma unroll
      for (int j = 0; j < 8; ++j) acc[i][j] = 0.f;
    }
  }
  stats_r2c8(acc, stat + (size_t)(blockIdx.x & (NSH - 1)) * 128, t, cg);
}

__global__ __launch_bounds__(256) void node_gemm2_v3(
    const float* __restrict__ u1, const float* __restrict__ ac,
    const float* __restrict__ W, const float* __restrict__ b,
    float* __restrict__ u2, float* __restrict__ stat, int N) {
  __shared__ __align__(16) float As[64 * ASW];
  int n0 = blockIdx.x * 64;
  int t = threadIdx.x;
  int c = t & 63, g = t >> 6;
  float a1 = ac[c], c1 = ac[64 + c];
  for (int n = g; n < 64; n += 4) {
    int idx = n0 + n;
    bool v = idx < N;
    As[c * ASW + n] = v ? fmaxf(u1[(size_t)idx * 64 + c] * a1 + c1, 0.f) : 0.f;
  }
  __syncthreads();
  int rg = t >> 3, cg = t & 7;
  float acc[2][8];
#pragma unroll
  for (int i = 0; i < 2; ++i)
#pragma unroll
    for (int j = 0; j < 8; ++j) acc[i][j] = b[cg * 8 + j];
  gemm_r2c8(As, W, 64, rg, cg, acc);
#pragma unroll
  for (int i = 0; i < 2; ++i) {
    int idx = n0 + rg * 2 + i;
    if (idx < N) {
      *(float4*)&u2[(size_t)idx * 64 + cg * 8] =
          make_float4(acc[i][0], acc[i][1], acc[i][2], acc[i][3]);
      *(float4*)&u2[(size_t)idx * 64 + cg * 8 + 4] =
          make_float4(acc[i][4], acc[i][5], acc[i][6], acc[i][7]);
    } else {
#pragma unroll
      for (int j = 0; j < 8; ++j) acc[i][j] = 0.f;
    }
  }
  stats_r2c8(acc, stat + (size_t)(blockIdx.x & (NSH - 1)) * 128, t, cg);
}

__global__ void residual_kernel(float* __restrict__ h, short* __restrict__ hb,
                                const float* __restrict__ u2,
                                const float* __restrict__ ac, int total) {
  int gid = blockIdx.x * blockDim.x + threadIdx.x;
  if (gid >= total) return;
  int o = gid & 63;
  float v = u2[gid] * ac[o] + ac[64 + o];
  float nv = h[gid] + fmaxf(v, 0.f);
  h[gid] = nv;
  hb[gid] = f2bs(nv);
}

__global__ void pred_kernel(const float* __restrict__ h,
                            const float* __restrict__ W,
                            const float* __restrict__ b,
                            float* __restrict__ out, int N) {
  int n = blockIdx.x * blockDim.x + threadIdx.x;
  if (n >= N) return;
  float acc = b[0];
  const float* hr = h + (size_t)n * 64;
#pragma unroll
  for (int o = 0; o < 64; ++o) acc += hr[o] * W[o];
  out[n] = acc;
}

// ---- launch ----------------------------------------------------------------

extern "C" void kernel_launch(void* const* d_in, const int* in_sizes, int n_in,
                              void* d_out, int out_size, void* d_ws,
                              size_t ws_size, hipStream_t stream) {
  const float* x = (const float*)d_in[0];
  const int* ei = (const int*)d_in[1];
  const float* ea = (const float*)d_in[2];
  const float* lin_W = (const float*)d_in[3];
  const float* lin_b = (const float*)d_in[4];
  const float* msg_W1 = (const float*)d_in[5];
  const float* msg_b1 = (const float*)d_in[6];
  const float* msg_g1 = (const float*)d_in[7];
  const float* msg_be1 = (const float*)d_in[8];
  const float* msg_W2 = (const float*)d_in[9];
  const float* msg_b2 = (const float*)d_in[10];
  const float* msg_g2 = (const float*)d_in[11];
  const float* msg_be2 = (const float*)d_in[12];
  const float* upd_W1 = (const float*)d_in[13];
  const float* upd_b1 = (const float*)d_in[14];
  const float* upd_g1 = (const float*)d_in[15];
  const float* upd_be1 = (const float*)d_in[16];
  const float* upd_W2 = (const float*)d_in[17];
  const float* upd_b2 = (const float*)d_in[18];
  const float* upd_g2 = (const float*)d_in[19];
  const float* upd_be2 = (const float*)d_in[20];
  const float* pred_W = (const float*)d_in[21];
  const float* pred_b = (const float*)d_in[22];
  float* out = (float*)d_out;

  const int N = in_sizes[0] / 6;
  const int E = in_sizes[1] / 2;
  const int L = 4;
  const int Epad = ((E + 127) / 128) * 128;

  char* p = (char*)d_ws;
  auto alloc = [&](size_t bytes) {
    void* r = (void*)p;
    p += (bytes + 255) & ~(size_t)255;
    return r;
  };
  float* h = (float*)alloc((size_t)N * 64 * 4);
  short* hb = (short*)alloc((size_t)N * 64 * 2);
  float* aggr = (float*)alloc((size_t)N * 64 * 4);
  float* u1 = (float*)alloc((size_t)N * 64 * 4);
  float* u2 = (float*)alloc((size_t)N * 64 * 4);
  float* stats = (float*)alloc((size_t)4 * NSH * 128 * 4);
  float* ac1 = (float*)alloc(128 * 4);
  float* ac2 = (float*)alloc(128 * 4);
  float* acu1 = (float*)alloc(128 * 4);
  float* acu2 = (float*)alloc(128 * 4);
  float* b1s = (float*)alloc(64 * 4);
  float* b2s = (float*)alloc(64 * 4);
  int* deg = (int*)alloc((size_t)N * 4);
  int* offs = (int*)alloc((size_t)N * 4);
  int* cnt = (int*)alloc((size_t)N * 4);
  int* sorted = (int*)alloc((size_t)E * 4);
  int* dd = (int*)alloc((size_t)Epad * 4);
  int* dsr = (int*)alloc((size_t)Epad * 4);
  short* es = (short*)alloc((size_t)Epad * 2);
  short* Wt1 = (short*)alloc((size_t)L * 64 * 160 * 2);
  short* Wt2 = (short*)alloc((size_t)L * 64 * 64 * 2);
  short* Wt1s = (short*)alloc((size_t)64 * 160 * 2);
  short* Wt2s = (short*)alloc((size_t)64 * 64 * 2);

  const int B = 256;
  const size_t REG = (size_t)NSH * 128;
  int gridE256 = (E + 255) / 256;
  int gridEb = Epad / 128;
  int gridM64 = (N + 63) / 64;
  int gridN64 = (N * 64 + B - 1) / B;
  int gridN = (N + B - 1) / B;

  // setup
  hipMemsetAsync(deg, 0, (size_t)N * 4, stream);
  hipMemsetAsync(cnt, 0, (size_t)N * 4, stream);
  lin_in_kernel<<<gridN64, B, 0, stream>>>(x, lin_W, lin_b, h, hb, N);
  deg_kernel<<<gridE256, B, 0, stream>>>(ei, deg, E);
  scan_kernel<<<1, 1024, 0, stream>>>(deg, offs, N);
  fill_kernel<<<gridE256, B, 0, stream>>>(ei, offs, cnt, sorted, E);
  gather_edges_kernel<<<(Epad + 255) / 256, B, 0, stream>>>(ei, sorted, ea, dd,
                                                            dsr, es, E, Epad);
  pack_w1_kernel<<<(L * 64 * 160 + 255) / 256, B, 0, stream>>>(msg_W1, Wt1, L);
  pack_w2_kernel<<<(L * 64 * 64 + 255) / 256, B, 0, stream>>>(msg_W2, Wt2, L);

  for (int l = 0; l < L; ++l) {
    const short* Wt1l = Wt1 + (size_t)l * 64 * 160;
    const short* Wt2l = Wt2 + (size_t)l * 64 * 64;
    const float* U1 = upd_W1 + (size_t)l * 128 * 64;
    const float* U2 = upd_W2 + (size_t)l * 64 * 64;
    hipMemsetAsync(stats, 0, (size_t)4 * REG * 4, stream);
    hipMemsetAsync(aggr, 0, (size_t)N * 64 * 4, stream);
    edge_pass_a<<<gridEb, 256, 0, stream>>>(hb, Wt1l, msg_b1 + l * 64, dd, dsr,
                                            es, stats, E);
    bn_finalize_kernel<<<1, 64, 0, stream>>>(stats, msg_g1 + l * 64,
                                             msg_be1 + l * 64, (float)E, ac1);
    pack_w1s_kernel<<<(64 * 160 + 255) / 256, B, 0, stream>>>(
        msg_W1 + (size_t)l * 129 * 64, msg_b1 + l * 64, ac1, Wt1s, b1s);
    edge_pass_b<<<gridEb, 256, 0, stream>>>(hb, Wt1s, b1s, dd, dsr, es, Wt2l,
                                            msg_b2 + l * 64, stats + REG, E);
    bn_finalize_kernel<<<1, 64, 0, stream>>>(stats + REG, msg_g2 + l * 64,
                                             msg_be2 + l * 64, (float)E, ac2);
    pack_w2s_kernel<<<(64 * 64 + 255) / 256, B, 0, stream>>>(
        msg_W2 + (size_t)l * 64 * 64, msg_b2 + l * 64, ac2, Wt2s, b2s);
    edge_pass_c<<<gridEb, 256, 0, stream>>>(hb, Wt1s, b1s, dd, dsr, es, Wt2s,
                                            b2s, aggr, E);
    node_gemm1_v3<<<gridM64, 256, 0, stream>>>(h, aggr, U1, upd_b1 + l * 64,
                                               u1, stats + 2 * REG, N);
    bn_finalize_kernel<<<1, 64, 0, stream>>>(stats + 2 * REG, upd_g1 + l * 64,
                                             upd_be1 + l * 64, (float)N, acu1);
    node_gemm2_v3<<<gridM64, 256, 0, stream>>>(u1, acu1, U2, upd_b2 + l * 64,
                                               u2, stats + 3 * REG, N);
    bn_finalize_kernel<<<1, 64, 0, stream>>>(stats + 3 * REG, upd_g2 + l * 64,
                                             upd_be2 + l * 64, (float)N, acu2);
    residual_kernel<<<gridN64, B, 0, stream>>>(h, hb, u2, acu2, N * 64);
  }
  pred_kernel<<<gridN, B, 0, stream>>>(h, pred_W, pred_b, out, N);
}

// Round 9
// 2424.973 us; speedup vs baseline: 1.3979x; 1.0537x over previous
//
#include <hip/hip_runtime.h>
#include <hip/hip_bf16.h>

// MPNN, fp32 tensors / int32 edge_index. Round-9: edge MLPs move to
// v_mfma_f32_32x32x16_bf16. Wave owns a 32-edge m-tile x all 64 cols
// (2 n-tiles): A-gather instr/block 128->32 (r8 had 4x wave redundancy),
// MFMA instr 224->104, GEMM2 LDS reads 64->16 b128. C layout (verified):
// col=lane&31, row=(reg&3)+8*(reg>>2)+4*(lane>>5). BN folded into repacked
// weights (r8); bn_finalize fused with repack. Segsum vectorized (b32
// col-pairs). Node pipeline unchanged (r5 fp32 tiled).

#define BN_EPS 1e-5f
#define NSH 128
#define LYS 72   // LDS y-tile row stride in shorts (144B rows, 16B-aligned)
#define ASW 66   // node-kernel LDS stride

typedef __attribute__((ext_vector_type(8))) short short8;
typedef __attribute__((ext_vector_type(16))) float floatx16;

#define MFMA32 __builtin_amdgcn_mfma_f32_32x32x16_bf16

__device__ __forceinline__ short f2bs(float f) {  // RNE
  union { float f; unsigned u; } x; x.f = f;
  unsigned r = x.u + 0x7fffu + ((x.u >> 16) & 1u);
  return (short)(r >> 16);
}
__device__ __forceinline__ short f2bs_fast(float f) {  // round-half-up
  union { float f; unsigned u; } x; x.f = f;
  return (short)((x.u + 0x8000u) >> 16);
}
__device__ __forceinline__ float bs2f(short s) {
  union { unsigned u; float f; } x;
  x.u = ((unsigned)(unsigned short)s) << 16;
  return x.f;
}

// ---- setup kernels ---------------------------------------------------------

__global__ void lin_in_kernel(const float* __restrict__ x,
                              const float* __restrict__ W,
                              const float* __restrict__ b, float* __restrict__ h,
                              short* __restrict__ hb, int N) {
  int gid = blockIdx.x * blockDim.x + threadIdx.x;
  if (gid >= N * 64) return;
  int n = gid >> 6, o = gid & 63;
  float acc = b[o];
#pragma unroll
  for (int k = 0; k < 6; ++k) acc += x[n * 6 + k] * W[k * 64 + o];
  h[gid] = acc;
  hb[gid] = f2bs(acc);
}

__global__ void deg_kernel(const int* __restrict__ ei, int* __restrict__ deg,
                           int E) {
  int gid = blockIdx.x * blockDim.x + threadIdx.x;
  if (gid < E) atomicAdd(&deg[ei[E + gid]], 1);  // row 1 = dst
}

__global__ void scan_kernel(const int* __restrict__ deg, int* __restrict__ offs,
                            int N) {
  __shared__ int s[1024];
  int t = threadIdx.x;
  int chunk = (N + 1023) >> 10;
  int lo = t * chunk, hi = lo + chunk;
  if (hi > N) hi = N;
  if (lo > N) lo = N;
  int tot = 0;
  for (int i = lo; i < hi; ++i) tot += deg[i];
  s[t] = tot;
  __syncthreads();
  for (int off = 1; off < 1024; off <<= 1) {
    int v = (t >= off) ? s[t - off] : 0;
    __syncthreads();
    s[t] += v;
    __syncthreads();
  }
  int run = s[t] - tot;
  for (int i = lo; i < hi; ++i) {
    offs[i] = run;
    run += deg[i];
  }
}

__global__ void fill_kernel(const int* __restrict__ ei,
                            const int* __restrict__ offs, int* __restrict__ cnt,
                            int* __restrict__ sorted, int E) {
  int gid = blockIdx.x * blockDim.x + threadIdx.x;
  if (gid >= E) return;
  int d = ei[E + gid];
  int pos = offs[d] + atomicAdd(&cnt[d], 1);
  sorted[pos] = gid;
}

__global__ void gather_edges_kernel(const int* __restrict__ ei,
                                    const int* __restrict__ sorted,
                                    const float* __restrict__ ea,
                                    int* __restrict__ dd, int* __restrict__ ds,
                                    short* __restrict__ es, int E, int Epad) {
  int i = blockIdx.x * 256 + threadIdx.x;
  if (i >= Epad) return;
  if (i < E) {
    int e = sorted[i];
    dd[i] = ei[E + e];
    ds[i] = ei[e];
    es[i] = f2bs(ea[e]);
  } else {
    dd[i] = -1;
    ds[i] = 0;
    es[i] = 0;
  }
}

// msg_W1 (L,129,64) -> Wt1 (L,64,160) bf16 n-major, k zero-padded (plain)
__global__ void pack_w1_kernel(const float* __restrict__ W,
                               short* __restrict__ Wt, int L_) {
  int i = blockIdx.x * 256 + threadIdx.x;
  if (i >= L_ * 64 * 160) return;
  int k = i % 160, n = (i / 160) % 64, l = i / (160 * 64);
  Wt[i] = (k < 129) ? f2bs(W[((size_t)l * 129 + k) * 64 + n]) : (short)0;
}

// msg_W2 (L,64,64) -> Wt2 (L,64,64) bf16 n-major (plain)
__global__ void pack_w2_kernel(const float* __restrict__ W,
                               short* __restrict__ Wt, int L_) {
  int i = blockIdx.x * 256 + threadIdx.x;
  if (i >= L_ * 64 * 64) return;
  int k = i % 64, n = (i / 64) % 64, l = i / 4096;
  Wt[i] = f2bs(W[((size_t)l * 64 + k) * 64 + n]);
}

// reduce NSH shards -> BN scale/shift (node side)
__global__ void bn_finalize_kernel(const float* __restrict__ shards,
                                   const float* __restrict__ gamma,
                                   const float* __restrict__ beta, float cnt,
                                   float* __restrict__ ac) {
  int o = threadIdx.x;  // 64 threads
  float s = 0.f, q = 0.f;
  for (int i = 0; i < NSH; ++i) {
    s += shards[i * 128 + o];
    q += shards[i * 128 + 64 + o];
  }
  float mu = s / cnt;
  float var = fmaxf(q / cnt - mu * mu, 0.f);
  float r = rsqrtf(var + BN_EPS);
  float g = gamma[o];
  ac[o] = g * r;
  ac[64 + o] = beta[o] - mu * g * r;
}

// fused: shard reduce -> BN(a,c) -> repack folded W1 (a*W, 64x160) + b1s
__global__ void bn_finalize_pack1(const float* __restrict__ shards,
                                  const float* __restrict__ gamma,
                                  const float* __restrict__ beta, float cnt,
                                  const float* __restrict__ W,  // 129x64 layer
                                  const float* __restrict__ b,
                                  short* __restrict__ Wt,
                                  float* __restrict__ bs) {
  __shared__ float sa[64];
  int t = threadIdx.x;
  if (t < 64) {
    float s = 0.f, q = 0.f;
    for (int i = 0; i < NSH; ++i) {
      s += shards[i * 128 + t];
      q += shards[i * 128 + 64 + t];
    }
    float mu = s / cnt;
    float var = fmaxf(q / cnt - mu * mu, 0.f);
    float r = rsqrtf(var + BN_EPS);
    float a = gamma[t] * r;
    float c = beta[t] - mu * a;
    sa[t] = a;
    if (blockIdx.x == 0) bs[t] = a * b[t] + c;
  }
  __syncthreads();
  int i = blockIdx.x * 256 + t;
  if (i < 64 * 160) {
    int k = i % 160, n = i / 160;
    Wt[i] = (k < 129) ? f2bs(W[k * 64 + n] * sa[n]) : (short)0;
  }
}

__global__ void bn_finalize_pack2(const float* __restrict__ shards,
                                  const float* __restrict__ gamma,
                                  const float* __restrict__ beta, float cnt,
                                  const float* __restrict__ W,  // 64x64 layer
                                  const float* __restrict__ b,
                                  short* __restrict__ Wt,
                                  float* __restrict__ bs) {
  __shared__ float sa[64];
  int t = threadIdx.x;
  if (t < 64) {
    float s = 0.f, q = 0.f;
    for (int i = 0; i < NSH; ++i) {
      s += shards[i * 128 + t];
      q += shards[i * 128 + 64 + t];
    }
    float mu = s / cnt;
    float var = fmaxf(q / cnt - mu * mu, 0.f);
    float r = rsqrtf(var + BN_EPS);
    float a = gamma[t] * r;
    float c = beta[t] - mu * a;
    sa[t] = a;
    if (blockIdx.x == 0) bs[t] = a * b[t] + c;
  }
  __syncthreads();
  int i = blockIdx.x * 256 + t;
  if (i < 64 * 64) {
    int k = i % 64, n = i / 64;
    Wt[i] = f2bs(W[k * 64 + n] * sa[n]);
  }
}

// ---- 32x32x16 MFMA edge helpers --------------------------------------------
// Block 256 thr = 4 waves. Wave w owns edges [idx0+32w, +32) and ALL 64 cols
// (2 n-tiles of 32). A: m=lane&31(edge), k=(lane>>5)*8+j. B: n=lane&31,
// k=(lane>>5)*8+j (from n-major pack). C: col=lane&31,
// row=(reg&3)+8*(reg>>2)+4*(lane>>5).

__device__ __forceinline__ void gemm1_32(
    const short* __restrict__ hbf, const short* __restrict__ Wt,
    const float* __restrict__ bias, const int* sdst, const int* ssrc,
    const short* sea, int w, int me, int hl, floatx16 acc[2]) {
  int e = w * 32 + me;
  int d = sdst[e];
  d = d < 0 ? 0 : d;
  int sx = ssrc[e];
  const short* hd = hbf + (size_t)d * 64 + hl * 8;
  const short* hs = hbf + (size_t)sx * 64 + hl * 8;
  short8 A[8];
#pragma unroll
  for (int kc = 0; kc < 4; ++kc) A[kc] = *(const short8*)(hd + kc * 16);
#pragma unroll
  for (int kc = 0; kc < 4; ++kc) A[4 + kc] = *(const short8*)(hs + kc * 16);
  short8 a8 = {0, 0, 0, 0, 0, 0, 0, 0};
  if (hl == 0) a8[0] = sea[e];  // k=128 (ea row); k 129..159 zero-padded
#pragma unroll
  for (int nt = 0; nt < 2; ++nt) {
    int col = nt * 32 + me;
    float bv = bias[col];
    floatx16 a;
#pragma unroll
    for (int r = 0; r < 16; ++r) a[r] = bv;
    const short* wp = Wt + (size_t)col * 160 + hl * 8;
#pragma unroll
    for (int kc = 0; kc < 8; ++kc) {
      short8 B = *(const short8*)(wp + kc * 16);
      a = MFMA32(A[kc], B, a, 0, 0, 0);
    }
    short8 B8 = *(const short8*)(wp + 128);
    a = MFMA32(a8, B8, a, 0, 0, 0);  // chunk 8; chunk 9 all-zero: skipped
    acc[nt] = a;
  }
}

__device__ __forceinline__ void gemm2_32(const short* __restrict__ Ly,
                                         const short* __restrict__ Wt2,
                                         const float* __restrict__ bias, int w,
                                         int me, int hl, floatx16 acc[2]) {
  short8 Z[4];
  const short* zp = &Ly[(w * 32 + me) * LYS + hl * 8];
#pragma unroll
  for (int kc = 0; kc < 4; ++kc) Z[kc] = *(const short8*)(zp + kc * 16);
#pragma unroll
  for (int nt = 0; nt < 2; ++nt) {
    int col = nt * 32 + me;
    float bv = bias[col];
    floatx16 a;
#pragma unroll
    for (int r = 0; r < 16; ++r) a[r] = bv;
    const short* wp = Wt2 + (size_t)col * 64 + hl * 8;
#pragma unroll
    for (int kc = 0; kc < 4; ++kc) {
      short8 B = *(const short8*)(wp + kc * 16);
      a = MFMA32(Z[kc], B, a, 0, 0, 0);
    }
    acc[nt] = a;
  }
}

// col sums/sumsq (invalid edges masked) -> sred[w][128]
__device__ __forceinline__ void stats32(const floatx16 acc[2], int idx0, int w,
                                        int hl, int lane, int E, bool full,
                                        float* __restrict__ sredw) {
#pragma unroll
  for (int nt = 0; nt < 2; ++nt) {
    float s = 0.f, q = 0.f;
#pragma unroll
    for (int r = 0; r < 16; ++r) {
      float v = acc[nt][r];
      if (!full) {
        int row = (r & 3) + 8 * (r >> 2) + 4 * hl;
        if (idx0 + w * 32 + row >= E) v = 0.f;
      }
      s += v;
      q += v * v;
    }
    s += __shfl_down(s, 32, 64);
    q += __shfl_down(q, 32, 64);
    if (lane < 32) {
      sredw[nt * 32 + lane] = s;
      sredw[64 + nt * 32 + lane] = q;
    }
  }
}

// relu(+mask) -> bf16 -> Ly[edge][col], rows wave-private
__device__ __forceinline__ void write_ly(short* __restrict__ Ly,
                                         const floatx16 acc[2], int w, int me,
                                         int hl, bool mask, int idx0, int E) {
#pragma unroll
  for (int nt = 0; nt < 2; ++nt) {
    int col = nt * 32 + me;
#pragma unroll
    for (int r = 0; r < 16; ++r) {
      int row = (r & 3) + 8 * (r >> 2) + 4 * hl;
      float v = fmaxf(acc[nt][r], 0.f);
      if (mask && idx0 + w * 32 + row >= E) v = 0.f;
      Ly[(w * 32 + row) * LYS + col] = f2bs_fast(v);
    }
  }
}

// ---- edge pass kernels -----------------------------------------------------

__global__ __launch_bounds__(256) void edge_pass_a(
    const short* __restrict__ hbf, const short* __restrict__ Wt1,
    const float* __restrict__ b1, const int* __restrict__ dd,
    const int* __restrict__ dsr, const short* __restrict__ es,
    float* __restrict__ stat, int E) {
  __shared__ int sdst[128], ssrc[128];
  __shared__ short sea[128];
  __shared__ float sred[4][128];
  int t = threadIdx.x, idx0 = blockIdx.x * 128;
  if (t < 128) {
    sdst[t] = dd[idx0 + t];
    ssrc[t] = dsr[idx0 + t];
    sea[t] = es[idx0 + t];
  }
  __syncthreads();
  int w = t >> 6, lane = t & 63, me = lane & 31, hl = lane >> 5;
  floatx16 acc[2];
  gemm1_32(hbf, Wt1, b1, sdst, ssrc, sea, w, me, hl, acc);
  bool full = idx0 + 128 <= E;
  stats32(acc, idx0, w, hl, lane, E, full, sred[w]);
  __syncthreads();
  if (t < 128) {
    float v = sred[0][t] + sred[1][t] + sred[2][t] + sred[3][t];
    atomicAdd(&stat[(size_t)(blockIdx.x & (NSH - 1)) * 128 + t], v);
  }
}

__global__ __launch_bounds__(256) void edge_pass_b(
    const short* __restrict__ hbf, const short* __restrict__ Wt1s,
    const float* __restrict__ b1s, const int* __restrict__ dd,
    const int* __restrict__ dsr, const short* __restrict__ es,
    const short* __restrict__ Wt2, const float* __restrict__ b2,
    float* __restrict__ stat, int E) {
  __shared__ int sdst[128], ssrc[128];
  __shared__ short sea[128];
  __shared__ __align__(16) short Ly[128 * LYS];
  __shared__ float sred[4][128];
  int t = threadIdx.x, idx0 = blockIdx.x * 128;
  if (t < 128) {
    sdst[t] = dd[idx0 + t];
    ssrc[t] = dsr[idx0 + t];
    sea[t] = es[idx0 + t];
  }
  __syncthreads();
  int w = t >> 6, lane = t & 63, me = lane & 31, hl = lane >> 5;
  floatx16 acc[2];
  gemm1_32(hbf, Wt1s, b1s, sdst, ssrc, sea, w, me, hl, acc);
  write_ly(Ly, acc, w, me, hl, false, idx0, E);  // z (BN1 folded) to LDS
  // wave-private rows: no barrier (intra-wave DS ordering + lgkm waits)
  floatx16 acc2[2];
  gemm2_32(Ly, Wt2, b2, w, me, hl, acc2);  // raw y2 for stats
  bool full = idx0 + 128 <= E;
  stats32(acc2, idx0, w, hl, lane, E, full, sred[w]);
  __syncthreads();
  if (t < 128) {
    float v = sred[0][t] + sred[1][t] + sred[2][t] + sred[3][t];
    atomicAdd(&stat[(size_t)(blockIdx.x & (NSH - 1)) * 128 + t], v);
  }
}

__global__ __launch_bounds__(256) void edge_pass_c(
    const short* __restrict__ hbf, const short* __restrict__ Wt1s,
    const float* __restrict__ b1s, const int* __restrict__ dd,
    const int* __restrict__ dsr, const short* __restrict__ es,
    const short* __restrict__ Wt2s, const float* __restrict__ b2s,
    float* __restrict__ aggr, int E) {
  __shared__ int sdst[128], ssrc[128];
  __shared__ short sea[128];
  __shared__ __align__(16) short Ly[128 * LYS];
  int t = threadIdx.x, idx0 = blockIdx.x * 128;
  if (t < 128) {
    sdst[t] = dd[idx0 + t];
    ssrc[t] = dsr[idx0 + t];
    sea[t] = es[idx0 + t];
  }
  __syncthreads();
  int w = t >> 6, lane = t & 63, me = lane & 31, hl = lane >> 5;
  floatx16 acc[2];
  gemm1_32(hbf, Wt1s, b1s, sdst, ssrc, sea, w, me, hl, acc);
  write_ly(Ly, acc, w, me, hl, false, idx0, E);  // z to LDS (wave-private)
  floatx16 acc2[2];
  gemm2_32(Ly, Wt2s, b2s, w, me, hl, acc2);  // BN2-folded y2
  bool full = idx0 + 128 <= E;
  // overwrite own rows with relu(y2) (in-order after own reads)
  write_ly(Ly, acc2, w, me, hl, !full, idx0, E);
  __syncthreads();
  // segmented sum over dst-sorted runs; b32 col-pair reads; cross-block
  // partials via atomics; padded edges (dst=-1) never flush.
  int cp = t & 31, g = t >> 5;  // col pair (2 cols), 8 groups x 16 edges
  float s0 = 0.f, s1 = 0.f;
  int e0 = g * 16;
  for (int e = e0; e < e0 + 16; ++e) {
    int d2 = sdst[e];
    unsigned v = *(const unsigned*)&Ly[e * LYS + cp * 2];
    s0 += bs2f((short)(v & 0xffffu));
    s1 += bs2f((short)(v >> 16));
    int dn = (e == e0 + 15) ? -2 : sdst[e + 1];
    if (d2 != dn) {
      if (d2 >= 0) {
        atomicAdd(&aggr[(size_t)d2 * 64 + cp * 2], s0);
        atomicAdd(&aggr[(size_t)d2 * 64 + cp * 2 + 1], s1);
      }
      s0 = 0.f;
      s1 = 0.f;
    }
  }
}

// ---- node pipeline (round-5 fp32 tiled, unchanged) -------------------------

__device__ __forceinline__ void gemm_r2c8(const float* __restrict__ As,
                                          const float* __restrict__ W, int K,
                                          int rg, int cg, float acc[2][8]) {
  const float* ap = As + rg * 2;
  const float* wp = W + cg * 8;
#pragma unroll 4
  for (int k = 0; k < K; ++k) {
    float2 a = *(const float2*)&ap[k * ASW];
    float4 w0 = *(const float4*)&wp[k * 64];
    float4 w1 = *(const float4*)&wp[k * 64 + 4];
    float wv[8] = {w0.x, w0.y, w0.z, w0.w, w1.x, w1.y, w1.z, w1.w};
#pragma unroll
    for (int j = 0; j < 8; ++j) {
      acc[0][j] += a.x * wv[j];
      acc[1][j] += a.y * wv[j];
    }
  }
}

__device__ __forceinline__ void stats_r2c8(const float acc[2][8],
                                           float* __restrict__ shard, int t,
                                           int cg) {
  float s[8], q[8];
#pragma unroll
  for (int j = 0; j < 8; ++j) {
    s[j] = acc[0][j] + acc[1][j];
    q[j] = acc[0][j] * acc[0][j] + acc[1][j] * acc[1][j];
  }
#pragma unroll
  for (int off = 32; off >= 8; off >>= 1) {
#pragma unroll
    for (int j = 0; j < 8; ++j) {
      s[j] += __shfl_down(s[j], off, 64);
      q[j] += __shfl_down(q[j], off, 64);
    }
  }
  if (((t & 63) >> 3) == 0) {
#pragma unroll
    for (int j = 0; j < 8; ++j) {
      atomicAdd(&shard[cg * 8 + j], s[j]);
      atomicAdd(&shard[64 + cg * 8 + j], q[j]);
    }
  }
}

__global__ __launch_bounds__(256) void node_gemm1_v3(
    const float* __restrict__ h, const float* __restrict__ aggr,
    const float* __restrict__ W, const float* __restrict__ b,
    float* __restrict__ u1, float* __restrict__ stat, int N) {
  __shared__ __align__(16) float As[128 * ASW];
  int n0 = blockIdx.x * 64;
  int t = threadIdx.x;
  int c = t & 63, g = t >> 6;
  for (int n = g; n < 64; n += 4) {
    int idx = n0 + n;
    bool v = idx < N;
    As[c * ASW + n] = v ? h[(size_t)idx * 64 + c] : 0.f;
    As[(64 + c) * ASW + n] = v ? aggr[(size_t)idx * 64 + c] : 0.f;
  }
  __syncthreads();
  int rg = t >> 3, cg = t & 7;
  float acc[2][8];
#pragma unroll
  for (int i = 0; i < 2; ++i)
#pragma unroll
    for (int j = 0; j < 8; ++j) acc[i][j] = b[cg * 8 + j];
  gemm_r2c8(As, W, 128, rg, cg, acc);
#pragma unroll
  for (int i = 0; i < 2; ++i) {
    int idx = n0 + rg * 2 + i;
    if (idx < N) {
      *(float4*)&u1[(size_t)idx * 64 + cg * 8] =
          make_float4(acc[i][0], acc[i][1], acc[i][2], acc[i][3]);
      *(float4*)&u1[(size_t)idx * 64 + cg * 8 + 4] =
          make_float4(acc[i][4], acc[i][5], acc[i][6], acc[i][7]);
    } else {
#pragma unroll
      for (int j = 0; j < 8; ++j) acc[i][j] = 0.f;
    }
  }
  stats_r2c8(acc, stat + (size_t)(blockIdx.x & (NSH - 1)) * 128, t, cg);
}

__global__ __launch_bounds__(256) void node_gemm2_v3(
    const float* __restrict__ u1, const float* __restrict__ ac,
    const float* __restrict__ W, const float* __restrict__ b,
    float* __restrict__ u2, float* __restrict__ stat, int N) {
  __shared__ __align__(16) float As[64 * ASW];
  int n0 = blockIdx.x * 64;
  int t = threadIdx.x;
  int c = t & 63, g = t >> 6;
  float a1 = ac[c], c1 = ac[64 + c];
  for (int n = g; n < 64; n += 4) {
    int idx = n0 + n;
    bool v = idx < N;
    As[c * ASW + n] = v ? fmaxf(u1[(size_t)idx * 64 + c] * a1 + c1, 0.f) : 0.f;
  }
  __syncthreads();
  int rg = t >> 3, cg = t & 7;
  float acc[2][8];
#pragma unroll
  for (int i = 0; i < 2; ++i)
#pragma unroll
    for (int j = 0; j < 8; ++j) acc[i][j] = b[cg * 8 + j];
  gemm_r2c8(As, W, 64, rg, cg, acc);
#pragma unroll
  for (int i = 0; i < 2; ++i) {
    int idx = n0 + rg * 2 + i;
    if (idx < N) {
      *(float4*)&u2[(size_t)idx * 64 + cg * 8] =
          make_float4(acc[i][0], acc[i][1], acc[i][2], acc[i][3]);
      *(float4*)&u2[(size_t)idx * 64 + cg * 8 + 4] =
          make_float4(acc[i][4], acc[i][5], acc[i][6], acc[i][7]);
    } else {
#pragma unroll
      for (int j = 0; j < 8; ++j) acc[i][j] = 0.f;
    }
  }
  stats_r2c8(acc, stat + (size_t)(blockIdx.x & (NSH - 1)) * 128, t, cg);
}

__global__ void residual_kernel(float* __restrict__ h, short* __restrict__ hb,
                                const float* __restrict__ u2,
                                const float* __restrict__ ac, int total) {
  int gid = blockIdx.x * blockDim.x + threadIdx.x;
  if (gid >= total) return;
  int o = gid & 63;
  float v = u2[gid] * ac[o] + ac[64 + o];
  float nv = h[gid] + fmaxf(v, 0.f);
  h[gid] = nv;
  hb[gid] = f2bs(nv);
}

__global__ void pred_kernel(const float* __restrict__ h,
                            const float* __restrict__ W,
                            const float* __restrict__ b,
                            float* __restrict__ out, int N) {
  int n = blockIdx.x * blockDim.x + threadIdx.x;
  if (n >= N) return;
  float acc = b[0];
  const float* hr = h + (size_t)n * 64;
#pragma unroll
  for (int o = 0; o < 64; ++o) acc += hr[o] * W[o];
  out[n] = acc;
}

// ---- launch ----------------------------------------------------------------

extern "C" void kernel_launch(void* const* d_in, const int* in_sizes, int n_in,
                              void* d_out, int out_size, void* d_ws,
                              size_t ws_size, hipStream_t stream) {
  const float* x = (const float*)d_in[0];
  const int* ei = (const int*)d_in[1];
  const float* ea = (const float*)d_in[2];
  const float* lin_W = (const float*)d_in[3];
  const float* lin_b = (const float*)d_in[4];
  const float* msg_W1 = (const float*)d_in[5];
  const float* msg_b1 = (const float*)d_in[6];
  const float* msg_g1 = (const float*)d_in[7];
  const float* msg_be1 = (const float*)d_in[8];
  const float* msg_W2 = (const float*)d_in[9];
  const float* msg_b2 = (const float*)d_in[10];
  const float* msg_g2 = (const float*)d_in[11];
  const float* msg_be2 = (const float*)d_in[12];
  const float* upd_W1 = (const float*)d_in[13];
  const float* upd_b1 = (const float*)d_in[14];
  const float* upd_g1 = (const float*)d_in[15];
  const float* upd_be1 = (const float*)d_in[16];
  const float* upd_W2 = (const float*)d_in[17];
  const float* upd_b2 = (const float*)d_in[18];
  const float* upd_g2 = (const float*)d_in[19];
  const float* upd_be2 = (const float*)d_in[20];
  const float* pred_W = (const float*)d_in[21];
  const float* pred_b = (const float*)d_in[22];
  float* out = (float*)d_out;

  const int N = in_sizes[0] / 6;
  const int E = in_sizes[1] / 2;
  const int L = 4;
  const int Epad = ((E + 127) / 128) * 128;

  char* p = (char*)d_ws;
  auto alloc = [&](size_t bytes) {
    void* r = (void*)p;
    p += (bytes + 255) & ~(size_t)255;
    return r;
  };
  float* h = (float*)alloc((size_t)N * 64 * 4);
  short* hb = (short*)alloc((size_t)N * 64 * 2);
  float* aggr = (float*)alloc((size_t)N * 64 * 4);
  float* u1 = (float*)alloc((size_t)N * 64 * 4);
  float* u2 = (float*)alloc((size_t)N * 64 * 4);
  float* stats = (float*)alloc((size_t)4 * NSH * 128 * 4);
  float* acu1 = (float*)alloc(128 * 4);
  float* acu2 = (float*)alloc(128 * 4);
  float* b1s = (float*)alloc(64 * 4);
  float* b2s = (float*)alloc(64 * 4);
  int* deg = (int*)alloc((size_t)N * 4);
  int* offs = (int*)alloc((size_t)N * 4);
  int* cnt = (int*)alloc((size_t)N * 4);
  int* sorted = (int*)alloc((size_t)E * 4);
  int* dd = (int*)alloc((size_t)Epad * 4);
  int* dsr = (int*)alloc((size_t)Epad * 4);
  short* es = (short*)alloc((size_t)Epad * 2);
  short* Wt1 = (short*)alloc((size_t)L * 64 * 160 * 2);
  short* Wt2 = (short*)alloc((size_t)L * 64 * 64 * 2);
  short* Wt1s = (short*)alloc((size_t)64 * 160 * 2);
  short* Wt2s = (short*)alloc((size_t)64 * 64 * 2);

  const int B = 256;
  const size_t REG = (size_t)NSH * 128;
  int gridE256 = (E + 255) / 256;
  int gridEb = Epad / 128;
  int gridM64 = (N + 63) / 64;
  int gridN64 = (N * 64 + B - 1) / B;
  int gridN = (N + B - 1) / B;

  // setup
  hipMemsetAsync(deg, 0, (size_t)N * 4, stream);
  hipMemsetAsync(cnt, 0, (size_t)N * 4, stream);
  lin_in_kernel<<<gridN64, B, 0, stream>>>(x, lin_W, lin_b, h, hb, N);
  deg_kernel<<<gridE256, B, 0, stream>>>(ei, deg, E);
  scan_kernel<<<1, 1024, 0, stream>>>(deg, offs, N);
  fill_kernel<<<gridE256, B, 0, stream>>>(ei, offs, cnt, sorted, E);
  gather_edges_kernel<<<(Epad + 255) / 256, B, 0, stream>>>(ei, sorted, ea, dd,
                                                            dsr, es, E, Epad);
  pack_w1_kernel<<<(L * 64 * 160 + 255) / 256, B, 0, stream>>>(msg_W1, Wt1, L);
  pack_w2_kernel<<<(L * 64 * 64 + 255) / 256, B, 0, stream>>>(msg_W2, Wt2, L);

  for (int l = 0; l < L; ++l) {
    const short* Wt1l = Wt1 + (size_t)l * 64 * 160;
    const short* Wt2l = Wt2 + (size_t)l * 64 * 64;
    const float* U1 = upd_W1 + (size_t)l * 128 * 64;
    const float* U2 = upd_W2 + (size_t)l * 64 * 64;
    hipMemsetAsync(stats, 0, (size_t)4 * REG * 4, stream);
    hipMemsetAsync(aggr, 0, (size_t)N * 64 * 4, stream);
    edge_pass_a<<<gridEb, 256, 0, stream>>>(hb, Wt1l, msg_b1 + l * 64, dd, dsr,
                                            es, stats, E);
    bn_finalize_pack1<<<(64 * 160 + 255) / 256, B, 0, stream>>>(
        stats, msg_g1 + l * 64, msg_be1 + l * 64, (float)E,
        msg_W1 + (size_t)l * 129 * 64, msg_b1 + l * 64, Wt1s, b1s);
    edge_pass_b<<<gridEb, 256, 0, stream>>>(hb, Wt1s, b1s, dd, dsr, es, Wt2l,
                                            msg_b2 + l * 64, stats + REG, E);
    bn_finalize_pack2<<<(64 * 64 + 255) / 256, B, 0, stream>>>(
        stats + REG, msg_g2 + l * 64, msg_be2 + l * 64, (float)E,
        msg_W2 + (size_t)l * 64 * 64, msg_b2 + l * 64, Wt2s, b2s);
    edge_pass_c<<<gridEb, 256, 0, stream>>>(hb, Wt1s, b1s, dd, dsr, es, Wt2s,
                                            b2s, aggr, E);
    node_gemm1_v3<<<gridM64, 256, 0, stream>>>(h, aggr, U1, upd_b1 + l * 64,
                                               u1, stats + 2 * REG, N);
    bn_finalize_kernel<<<1, 64, 0, stream>>>(stats + 2 * REG, upd_g1 + l * 64,
                                             upd_be1 + l * 64, (float)N, acu1);
    node_gemm2_v3<<<gridM64, 256, 0, stream>>>(u1, acu1, U2, upd_b2 + l * 64,
                                               u2, stats + 3 * REG, N);
    bn_finalize_kernel<<<1, 64, 0, stream>>>(stats + 3 * REG, upd_g2 + l * 64,
                                             upd_be2 + l * 64, (float)N, acu2);
    residual_kernel<<<gridN64, B, 0, stream>>>(h, hb, u2, acu2, N * 64);
  }
  pred_kernel<<<gridN, B, 0, stream>>>(h, pred_W, pred_b, out, N);
}

// Round 10
// 2081.568 us; speedup vs baseline: 1.6285x; 1.1650x over previous
//
#include <hip/hip_runtime.h>
#include <hip/hip_bf16.h>

// MPNN, fp32 tensors / int32 edge_index. Round-10: r9's 32x32x16 MFMA edge
// passes were L1-BW-bound (every wave re-read full W1/W2 from global: ~110 KB
// L1/block, 4x redundant). Fix: stage W1 (64x168 LDS) + W2 (64x68 LDS) once
// per block, B-frags via ds_read_b128. Idx loads direct-global in a/b.
// Segsum reverted to r8 scheme (64 cols x 32-edge windows; r9's col-pairs
// tripled atomic WRITE traffic). Node pipeline unchanged (r5 fp32 tiled).

#define BN_EPS 1e-5f
#define NSH 128
#define LYS 72    // Ly row stride (shorts)
#define LW1S 168  // W1 LDS col stride (shorts; 84 words -> ~4-way max)
#define LW2S 68   // W2 LDS col stride (shorts; 34 words -> ~2-way)
#define ASW 66    // node-kernel LDS stride

typedef __attribute__((ext_vector_type(8))) short short8;
typedef __attribute__((ext_vector_type(16))) float floatx16;

#define MFMA32 __builtin_amdgcn_mfma_f32_32x32x16_bf16

__device__ __forceinline__ short f2bs(float f) {  // RNE
  union { float f; unsigned u; } x; x.f = f;
  unsigned r = x.u + 0x7fffu + ((x.u >> 16) & 1u);
  return (short)(r >> 16);
}
__device__ __forceinline__ short f2bs_fast(float f) {  // round-half-up
  union { float f; unsigned u; } x; x.f = f;
  return (short)((x.u + 0x8000u) >> 16);
}
__device__ __forceinline__ float bs2f(short s) {
  union { unsigned u; float f; } x;
  x.u = ((unsigned)(unsigned short)s) << 16;
  return x.f;
}

// ---- setup kernels ---------------------------------------------------------

__global__ void lin_in_kernel(const float* __restrict__ x,
                              const float* __restrict__ W,
                              const float* __restrict__ b, float* __restrict__ h,
                              short* __restrict__ hb, int N) {
  int gid = blockIdx.x * blockDim.x + threadIdx.x;
  if (gid >= N * 64) return;
  int n = gid >> 6, o = gid & 63;
  float acc = b[o];
#pragma unroll
  for (int k = 0; k < 6; ++k) acc += x[n * 6 + k] * W[k * 64 + o];
  h[gid] = acc;
  hb[gid] = f2bs(acc);
}

__global__ void deg_kernel(const int* __restrict__ ei, int* __restrict__ deg,
                           int E) {
  int gid = blockIdx.x * blockDim.x + threadIdx.x;
  if (gid < E) atomicAdd(&deg[ei[E + gid]], 1);  // row 1 = dst
}

__global__ void scan_kernel(const int* __restrict__ deg, int* __restrict__ offs,
                            int N) {
  __shared__ int s[1024];
  int t = threadIdx.x;
  int chunk = (N + 1023) >> 10;
  int lo = t * chunk, hi = lo + chunk;
  if (hi > N) hi = N;
  if (lo > N) lo = N;
  int tot = 0;
  for (int i = lo; i < hi; ++i) tot += deg[i];
  s[t] = tot;
  __syncthreads();
  for (int off = 1; off < 1024; off <<= 1) {
    int v = (t >= off) ? s[t - off] : 0;
    __syncthreads();
    s[t] += v;
    __syncthreads();
  }
  int run = s[t] - tot;
  for (int i = lo; i < hi; ++i) {
    offs[i] = run;
    run += deg[i];
  }
}

__global__ void fill_kernel(const int* __restrict__ ei,
                            const int* __restrict__ offs, int* __restrict__ cnt,
                            int* __restrict__ sorted, int E) {
  int gid = blockIdx.x * blockDim.x + threadIdx.x;
  if (gid >= E) return;
  int d = ei[E + gid];
  int pos = offs[d] + atomicAdd(&cnt[d], 1);
  sorted[pos] = gid;
}

__global__ void gather_edges_kernel(const int* __restrict__ ei,
                                    const int* __restrict__ sorted,
                                    const float* __restrict__ ea,
                                    int* __restrict__ dd, int* __restrict__ ds,
                                    short* __restrict__ es, int E, int Epad) {
  int i = blockIdx.x * 256 + threadIdx.x;
  if (i >= Epad) return;
  if (i < E) {
    int e = sorted[i];
    dd[i] = ei[E + e];
    ds[i] = ei[e];
    es[i] = f2bs(ea[e]);
  } else {
    dd[i] = -1;
    ds[i] = 0;
    es[i] = 0;
  }
}

// msg_W1 (L,129,64) -> Wt1 (L,64,160) bf16 n-major, k zero-padded (plain)
__global__ void pack_w1_kernel(const float* __restrict__ W,
                               short* __restrict__ Wt, int L_) {
  int i = blockIdx.x * 256 + threadIdx.x;
  if (i >= L_ * 64 * 160) return;
  int k = i % 160, n = (i / 160) % 64, l = i / (160 * 64);
  Wt[i] = (k < 129) ? f2bs(W[((size_t)l * 129 + k) * 64 + n]) : (short)0;
}

// msg_W2 (L,64,64) -> Wt2 (L,64,64) bf16 n-major (plain)
__global__ void pack_w2_kernel(const float* __restrict__ W,
                               short* __restrict__ Wt, int L_) {
  int i = blockIdx.x * 256 + threadIdx.x;
  if (i >= L_ * 64 * 64) return;
  int k = i % 64, n = (i / 64) % 64, l = i / 4096;
  Wt[i] = f2bs(W[((size_t)l * 64 + k) * 64 + n]);
}

// reduce NSH shards -> BN scale/shift (node side)
__global__ void bn_finalize_kernel(const float* __restrict__ shards,
                                   const float* __restrict__ gamma,
                                   const float* __restrict__ beta, float cnt,
                                   float* __restrict__ ac) {
  int o = threadIdx.x;  // 64 threads
  float s = 0.f, q = 0.f;
  for (int i = 0; i < NSH; ++i) {
    s += shards[i * 128 + o];
    q += shards[i * 128 + 64 + o];
  }
  float mu = s / cnt;
  float var = fmaxf(q / cnt - mu * mu, 0.f);
  float r = rsqrtf(var + BN_EPS);
  float g = gamma[o];
  ac[o] = g * r;
  ac[64 + o] = beta[o] - mu * g * r;
}

// fused: shard reduce -> BN(a,c) -> repack folded W (a*W) + folded bias
__global__ void bn_finalize_pack1(const float* __restrict__ shards,
                                  const float* __restrict__ gamma,
                                  const float* __restrict__ beta, float cnt,
                                  const float* __restrict__ W,  // 129x64 layer
                                  const float* __restrict__ b,
                                  short* __restrict__ Wt,
                                  float* __restrict__ bs) {
  __shared__ float sa[64];
  int t = threadIdx.x;
  if (t < 64) {
    float s = 0.f, q = 0.f;
    for (int i = 0; i < NSH; ++i) {
      s += shards[i * 128 + t];
      q += shards[i * 128 + 64 + t];
    }
    float mu = s / cnt;
    float var = fmaxf(q / cnt - mu * mu, 0.f);
    float r = rsqrtf(var + BN_EPS);
    float a = gamma[t] * r;
    float c = beta[t] - mu * a;
    sa[t] = a;
    if (blockIdx.x == 0) bs[t] = a * b[t] + c;
  }
  __syncthreads();
  int i = blockIdx.x * 256 + t;
  if (i < 64 * 160) {
    int k = i % 160, n = i / 160;
    Wt[i] = (k < 129) ? f2bs(W[k * 64 + n] * sa[n]) : (short)0;
  }
}

__global__ void bn_finalize_pack2(const float* __restrict__ shards,
                                  const float* __restrict__ gamma,
                                  const float* __restrict__ beta, float cnt,
                                  const float* __restrict__ W,  // 64x64 layer
                                  const float* __restrict__ b,
                                  short* __restrict__ Wt,
                                  float* __restrict__ bs) {
  __shared__ float sa[64];
  int t = threadIdx.x;
  if (t < 64) {
    float s = 0.f, q = 0.f;
    for (int i = 0; i < NSH; ++i) {
      s += shards[i * 128 + t];
      q += shards[i * 128 + 64 + t];
    }
    float mu = s / cnt;
    float var = fmaxf(q / cnt - mu * mu, 0.f);
    float r = rsqrtf(var + BN_EPS);
    float a = gamma[t] * r;
    float c = beta[t] - mu * a;
    sa[t] = a;
    if (blockIdx.x == 0) bs[t] = a * b[t] + c;
  }
  __syncthreads();
  int i = blockIdx.x * 256 + t;
  if (i < 64 * 64) {
    int k = i % 64, n = i / 64;
    Wt[i] = f2bs(W[k * 64 + n] * sa[n]);
  }
}

// ---- 32x32x16 MFMA edge helpers --------------------------------------------
// Block 256 thr = 4 waves. Wave w owns edges [idx0+32w, +32), all 64 cols
// (2 n-tiles of 32). A: m=lane&31, k=(lane>>5)*8+j. B from LDS-staged W.
// C: col=lane&31, row=(reg&3)+8*(reg>>2)+4*(lane>>5).

// stage W1 (64 cols x 160 shorts) -> Lw[col*LW1S + ...]; 1280 b128 chunks
__device__ __forceinline__ void stage_w1(const short* __restrict__ Wt,
                                         short* Lw, int t) {
#pragma unroll
  for (int i = 0; i < 5; ++i) {
    int c = t + i * 256;  // 0..1279
    int col = c / 20, ch = c % 20;
    *(short8*)&Lw[col * LW1S + ch * 8] = *(const short8*)&Wt[col * 160 + ch * 8];
  }
}
// stage W2 (64 cols x 64 shorts); 512 chunks
__device__ __forceinline__ void stage_w2(const short* __restrict__ Wt,
                                         short* Lw, int t) {
#pragma unroll
  for (int i = 0; i < 2; ++i) {
    int c = t + i * 256;  // 0..511
    int col = c >> 3, ch = c & 7;
    *(short8*)&Lw[col * LW2S + ch * 8] = *(const short8*)&Wt[col * 64 + ch * 8];
  }
}

__device__ __forceinline__ void gemm1_32(const short* __restrict__ hbf,
                                         const short* Lw1,
                                         const float* __restrict__ bias, int d,
                                         int sx, short eav, int me, int hl,
                                         floatx16 acc[2]) {
  const short* hd = hbf + (size_t)d * 64 + hl * 8;
  const short* hs = hbf + (size_t)sx * 64 + hl * 8;
  short8 A[8];
#pragma unroll
  for (int kc = 0; kc < 4; ++kc) A[kc] = *(const short8*)(hd + kc * 16);
#pragma unroll
  for (int kc = 0; kc < 4; ++kc) A[4 + kc] = *(const short8*)(hs + kc * 16);
  short8 a8 = {0, 0, 0, 0, 0, 0, 0, 0};
  if (hl == 0) a8[0] = eav;  // k=128 (ea); k 129..159 zero-padded
#pragma unroll
  for (int nt = 0; nt < 2; ++nt) {
    int col = nt * 32 + me;
    float bv = bias[col];
    floatx16 a;
#pragma unroll
    for (int r = 0; r < 16; ++r) a[r] = bv;
    const short* wp = Lw1 + col * LW1S + hl * 8;
#pragma unroll
    for (int kc = 0; kc < 8; ++kc) {
      short8 B = *(const short8*)(wp + kc * 16);
      a = MFMA32(A[kc], B, a, 0, 0, 0);
    }
    short8 B8 = *(const short8*)(wp + 128);
    a = MFMA32(a8, B8, a, 0, 0, 0);
    acc[nt] = a;
  }
}

__device__ __forceinline__ void gemm2_32(const short* Ly, const short* Lw2,
                                         const float* __restrict__ bias, int w,
                                         int me, int hl, floatx16 acc[2]) {
  short8 Z[4];
  const short* zp = &Ly[(w * 32 + me) * LYS + hl * 8];
#pragma unroll
  for (int kc = 0; kc < 4; ++kc) Z[kc] = *(const short8*)(zp + kc * 16);
#pragma unroll
  for (int nt = 0; nt < 2; ++nt) {
    int col = nt * 32 + me;
    float bv = bias[col];
    floatx16 a;
#pragma unroll
    for (int r = 0; r < 16; ++r) a[r] = bv;
    const short* wp = Lw2 + col * LW2S + hl * 8;
#pragma unroll
    for (int kc = 0; kc < 4; ++kc) {
      short8 B = *(const short8*)(wp + kc * 16);
      a = MFMA32(Z[kc], B, a, 0, 0, 0);
    }
    acc[nt] = a;
  }
}

__device__ __forceinline__ void stats32(const floatx16 acc[2], int idx0, int w,
                                        int hl, int lane, int E, bool full,
                                        float* sredw) {
#pragma unroll
  for (int nt = 0; nt < 2; ++nt) {
    float s = 0.f, q = 0.f;
#pragma unroll
    for (int r = 0; r < 16; ++r) {
      float v = acc[nt][r];
      if (!full) {
        int row = (r & 3) + 8 * (r >> 2) + 4 * hl;
        if (idx0 + w * 32 + row >= E) v = 0.f;
      }
      s += v;
      q += v * v;
    }
    s += __shfl_down(s, 32, 64);
    q += __shfl_down(q, 32, 64);
    if (lane < 32) {
      sredw[nt * 32 + lane] = s;
      sredw[64 + nt * 32 + lane] = q;
    }
  }
}

__device__ __forceinline__ void write_ly(short* Ly, const floatx16 acc[2],
                                         int w, int me, int hl, bool mask,
                                         int idx0, int E) {
#pragma unroll
  for (int nt = 0; nt < 2; ++nt) {
    int col = nt * 32 + me;
#pragma unroll
    for (int r = 0; r < 16; ++r) {
      int row = (r & 3) + 8 * (r >> 2) + 4 * hl;
      float v = fmaxf(acc[nt][r], 0.f);
      if (mask && idx0 + w * 32 + row >= E) v = 0.f;
      Ly[(w * 32 + row) * LYS + col] = f2bs_fast(v);
    }
  }
}

// ---- edge pass kernels -----------------------------------------------------

__global__ __launch_bounds__(256) void edge_pass_a(
    const short* __restrict__ hbf, const short* __restrict__ Wt1,
    const float* __restrict__ b1, const int* __restrict__ dd,
    const int* __restrict__ dsr, const short* __restrict__ es,
    float* __restrict__ stat, int E) {
  __shared__ __align__(16) short Lw1[64 * LW1S];
  __shared__ float sred[4][128];
  int t = threadIdx.x, idx0 = blockIdx.x * 128;
  stage_w1(Wt1, Lw1, t);
  __syncthreads();
  int w = t >> 6, lane = t & 63, me = lane & 31, hl = lane >> 5;
  int eg = idx0 + w * 32 + me;
  int d = dd[eg];
  int dc = d < 0 ? 0 : d;
  int sx = dsr[eg];
  short eav = es[eg];
  floatx16 acc[2];
  gemm1_32(hbf, Lw1, b1, dc, sx, eav, me, hl, acc);
  bool full = idx0 + 128 <= E;
  stats32(acc, idx0, w, hl, lane, E, full, sred[w]);
  __syncthreads();
  if (t < 128) {
    float v = sred[0][t] + sred[1][t] + sred[2][t] + sred[3][t];
    atomicAdd(&stat[(size_t)(blockIdx.x & (NSH - 1)) * 128 + t], v);
  }
}

__global__ __launch_bounds__(256) void edge_pass_b(
    const short* __restrict__ hbf, const short* __restrict__ Wt1s,
    const float* __restrict__ b1s, const int* __restrict__ dd,
    const int* __restrict__ dsr, const short* __restrict__ es,
    const short* __restrict__ Wt2, const float* __restrict__ b2,
    float* __restrict__ stat, int E) {
  __shared__ __align__(16) short Lw1[64 * LW1S];
  __shared__ __align__(16) short Lw2[64 * LW2S];
  __shared__ __align__(16) short Ly[128 * LYS];
  __shared__ float sred[4][128];
  int t = threadIdx.x, idx0 = blockIdx.x * 128;
  stage_w1(Wt1s, Lw1, t);
  stage_w2(Wt2, Lw2, t);
  __syncthreads();
  int w = t >> 6, lane = t & 63, me = lane & 31, hl = lane >> 5;
  int eg = idx0 + w * 32 + me;
  int d = dd[eg];
  int dc = d < 0 ? 0 : d;
  int sx = dsr[eg];
  short eav = es[eg];
  floatx16 acc[2];
  gemm1_32(hbf, Lw1, b1s, dc, sx, eav, me, hl, acc);
  write_ly(Ly, acc, w, me, hl, false, idx0, E);  // z (BN1 folded), wave-private
  floatx16 acc2[2];
  gemm2_32(Ly, Lw2, b2, w, me, hl, acc2);  // raw y2 for stats
  bool full = idx0 + 128 <= E;
  stats32(acc2, idx0, w, hl, lane, E, full, sred[w]);
  __syncthreads();
  if (t < 128) {
    float v = sred[0][t] + sred[1][t] + sred[2][t] + sred[3][t];
    atomicAdd(&stat[(size_t)(blockIdx.x & (NSH - 1)) * 128 + t], v);
  }
}

__global__ __launch_bounds__(256) void edge_pass_c(
    const short* __restrict__ hbf, const short* __restrict__ Wt1s,
    const float* __restrict__ b1s, const int* __restrict__ dd,
    const int* __restrict__ dsr, const short* __restrict__ es,
    const short* __restrict__ Wt2s, const float* __restrict__ b2s,
    float* __restrict__ aggr, int E) {
  __shared__ __align__(16) short Lw1[64 * LW1S];
  __shared__ __align__(16) short Lw2[64 * LW2S];
  __shared__ __align__(16) short Ly[128 * LYS];
  __shared__ int sdst[128];
  int t = threadIdx.x, idx0 = blockIdx.x * 128;
  if (t < 128) sdst[t] = dd[idx0 + t];
  stage_w1(Wt1s, Lw1, t);
  stage_w2(Wt2s, Lw2, t);
  __syncthreads();
  int w = t >> 6, lane = t & 63, me = lane & 31, hl = lane >> 5;
  int eg = idx0 + w * 32 + me;
  int d = sdst[w * 32 + me];
  int dc = d < 0 ? 0 : d;
  int sx = dsr[eg];
  short eav = es[eg];
  floatx16 acc[2];
  gemm1_32(hbf, Lw1, b1s, dc, sx, eav, me, hl, acc);
  write_ly(Ly, acc, w, me, hl, false, idx0, E);  // z, wave-private rows
  floatx16 acc2[2];
  gemm2_32(Ly, Lw2, b2s, w, me, hl, acc2);  // BN2-folded y2
  bool full = idx0 + 128 <= E;
  write_ly(Ly, acc2, w, me, hl, !full, idx0, E);  // overwrite own rows
  __syncthreads();
  // segmented sum over dst-sorted runs (r8 scheme: 64 cols x 32-edge windows)
  int scol = t & 63, g = t >> 6;
  float s = 0.f;
  int e0 = g * 32;
  for (int e = e0; e < e0 + 32; ++e) {
    int d2 = sdst[e];
    s += bs2f(Ly[e * LYS + scol]);
    int dn = (e == e0 + 31) ? -2 : sdst[e + 1];
    if (d2 != dn) {
      if (d2 >= 0) atomicAdd(&aggr[(size_t)d2 * 64 + scol], s);
      s = 0.f;
    }
  }
}

// ---- node pipeline (round-5 fp32 tiled, unchanged) -------------------------

__device__ __forceinline__ void gemm_r2c8(const float* __restrict__ As,
                                          const float* __restrict__ W, int K,
                                          int rg, int cg, float acc[2][8]) {
  const float* ap = As + rg * 2;
  const float* wp = W + cg * 8;
#pragma unroll 4
  for (int k = 0; k < K; ++k) {
    float2 a = *(const float2*)&ap[k * ASW];
    float4 w0 = *(const float4*)&wp[k * 64];
    float4 w1 = *(const float4*)&wp[k * 64 + 4];
    float wv[8] = {w0.x, w0.y, w0.z, w0.w, w1.x, w1.y, w1.z, w1.w};
#pragma unroll
    for (int j = 0; j < 8; ++j) {
      acc[0][j] += a.x * wv[j];
      acc[1][j] += a.y * wv[j];
    }
  }
}

__device__ __forceinline__ void stats_r2c8(const float acc[2][8],
                                           float* __restrict__ shard, int t,
                                           int cg) {
  float s[8], q[8];
#pragma unroll
  for (int j = 0; j < 8; ++j) {
    s[j] = acc[0][j] + acc[1][j];
    q[j] = acc[0][j] * acc[0][j] + acc[1][j] * acc[1][j];
  }
#pragma unroll
  for (int off = 32; off >= 8; off >>= 1) {
#pragma unroll
    for (int j = 0; j < 8; ++j) {
      s[j] += __shfl_down(s[j], off, 64);
      q[j] += __shfl_down(q[j], off, 64);
    }
  }
  if (((t & 63) >> 3) == 0) {
#pragma unroll
    for (int j = 0; j < 8; ++j) {
      atomicAdd(&shard[cg * 8 + j], s[j]);
      atomicAdd(&shard[64 + cg * 8 + j], q[j]);
    }
  }
}

__global__ __launch_bounds__(256) void node_gemm1_v3(
    const float* __restrict__ h, const float* __restrict__ aggr,
    const float* __restrict__ W, const float* __restrict__ b,
    float* __restrict__ u1, float* __restrict__ stat, int N) {
  __shared__ __align__(16) float As[128 * ASW];
  int n0 = blockIdx.x * 64;
  int t = threadIdx.x;
  int c = t & 63, g = t >> 6;
  for (int n = g; n < 64; n += 4) {
    int idx = n0 + n;
    bool v = idx < N;
    As[c * ASW + n] = v ? h[(size_t)idx * 64 + c] : 0.f;
    As[(64 + c) * ASW + n] = v ? aggr[(size_t)idx * 64 + c] : 0.f;
  }
  __syncthreads();
  int rg = t >> 3, cg = t & 7;
  float acc[2][8];
#pragma unroll
  for (int i = 0; i < 2; ++i)
#pragma unroll
    for (int j = 0; j < 8; ++j) acc[i][j] = b[cg * 8 + j];
  gemm_r2c8(As, W, 128, rg, cg, acc);
#pragma unroll
  for (int i = 0; i < 2; ++i) {
    int idx = n0 + rg * 2 + i;
    if (idx < N) {
      *(float4*)&u1[(size_t)idx * 64 + cg * 8] =
          make_float4(acc[i][0], acc[i][1], acc[i][2], acc[i][3]);
      *(float4*)&u1[(size_t)idx * 64 + cg * 8 + 4] =
          make_float4(acc[i][4], acc[i][5], acc[i][6], acc[i][7]);
    } else {
#pragma unroll
      for (int j = 0; j < 8; ++j) acc[i][j] = 0.f;
    }
  }
  stats_r2c8(acc, stat + (size_t)(blockIdx.x & (NSH - 1)) * 128, t, cg);
}

__global__ __launch_bounds__(256) void node_gemm2_v3(
    const float* __restrict__ u1, const float* __restrict__ ac,
    const float* __restrict__ W, const float* __restrict__ b,
    float* __restrict__ u2, float* __restrict__ stat, int N) {
  __shared__ __align__(16) float As[64 * ASW];
  int n0 = blockIdx.x * 64;
  int t = threadIdx.x;
  int c = t & 63, g = t >> 6;
  float a1 = ac[c], c1 = ac[64 + c];
  for (int n = g; n < 64; n += 4) {
    int idx = n0 + n;
    bool v = idx < N;
    As[c * ASW + n] = v ? fmaxf(u1[(size_t)idx * 64 + c] * a1 + c1, 0.f) : 0.f;
  }
  __syncthreads();
  int rg = t >> 3, cg = t & 7;
  float acc[2][8];
#pragma unroll
  for (int i = 0; i < 2; ++i)
#pragma unroll
    for (int j = 0; j < 8; ++j) acc[i][j] = b[cg * 8 + j];
  gemm_r2c8(As, W, 64, rg, cg, acc);
#pragma unroll
  for (int i = 0; i < 2; ++i) {
    int idx = n0 + rg * 2 + i;
    if (idx < N) {
      *(float4*)&u2[(size_t)idx * 64 + cg * 8] =
          make_float4(acc[i][0], acc[i][1], acc[i][2], acc[i][3]);
      *(float4*)&u2[(size_t)idx * 64 + cg * 8 + 4] =
          make_float4(acc[i][4], acc[i][5], acc[i][6], acc[i][7]);
    } else {
#pragma unroll
      for (int j = 0; j < 8; ++j) acc[i][j] = 0.f;
    }
  }
  stats_r2c8(acc, stat + (size_t)(blockIdx.x & (NSH - 1)) * 128, t, cg);
}

__global__ void residual_kernel(float* __restrict__ h, short* __restrict__ hb,
                                const float* __restrict__ u2,
                                const float* __restrict__ ac, int total) {
  int gid = blockIdx.x * blockDim.x + threadIdx.x;
  if (gid >= total) return;
  int o = gid & 63;
  float v = u2[gid] * ac[o] + ac[64 + o];
  float nv = h[gid] + fmaxf(v, 0.f);
  h[gid] = nv;
  hb[gid] = f2bs(nv);
}

__global__ void pred_kernel(const float* __restrict__ h,
                            const float* __restrict__ W,
                            const float* __restrict__ b,
                            float* __restrict__ out, int N) {
  int n = blockIdx.x * blockDim.x + threadIdx.x;
  if (n >= N) return;
  float acc = b[0];
  const float* hr = h + (size_t)n * 64;
#pragma unroll
  for (int o = 0; o < 64; ++o) acc += hr[o] * W[o];
  out[n] = acc;
}

// ---- launch ----------------------------------------------------------------

extern "C" void kernel_launch(void* const* d_in, const int* in_sizes, int n_in,
                              void* d_out, int out_size, void* d_ws,
                              size_t ws_size, hipStream_t stream) {
  const float* x = (const float*)d_in[0];
  const int* ei = (const int*)d_in[1];
  const float* ea = (const float*)d_in[2];
  const float* lin_W = (const float*)d_in[3];
  const float* lin_b = (const float*)d_in[4];
  const float* msg_W1 = (const float*)d_in[5];
  const float* msg_b1 = (const float*)d_in[6];
  const float* msg_g1 = (const float*)d_in[7];
  const float* msg_be1 = (const float*)d_in[8];
  const float* msg_W2 = (const float*)d_in[9];
  const float* msg_b2 = (const float*)d_in[10];
  const float* msg_g2 = (const float*)d_in[11];
  const float* msg_be2 = (const float*)d_in[12];
  const float* upd_W1 = (const float*)d_in[13];
  const float* upd_b1 = (const float*)d_in[14];
  const float* upd_g1 = (const float*)d_in[15];
  const float* upd_be1 = (const float*)d_in[16];
  const float* upd_W2 = (const float*)d_in[17];
  const float* upd_b2 = (const float*)d_in[18];
  const float* upd_g2 = (const float*)d_in[19];
  const float* upd_be2 = (const float*)d_in[20];
  const float* pred_W = (const float*)d_in[21];
  const float* pred_b = (const float*)d_in[22];
  float* out = (float*)d_out;

  const int N = in_sizes[0] / 6;
  const int E = in_sizes[1] / 2;
  const int L = 4;
  const int Epad = ((E + 127) / 128) * 128;

  char* p = (char*)d_ws;
  auto alloc = [&](size_t bytes) {
    void* r = (void*)p;
    p += (bytes + 255) & ~(size_t)255;
    return r;
  };
  float* h = (float*)alloc((size_t)N * 64 * 4);
  short* hb = (short*)alloc((size_t)N * 64 * 2);
  float* aggr = (float*)alloc((size_t)N * 64 * 4);
  float* u1 = (float*)alloc((size_t)N * 64 * 4);
  float* u2 = (float*)alloc((size_t)N * 64 * 4);
  float* stats = (float*)alloc((size_t)4 * NSH * 128 * 4);
  float* acu1 = (float*)alloc(128 * 4);
  float* acu2 = (float*)alloc(128 * 4);
  float* b1s = (float*)alloc(64 * 4);
  float* b2s = (float*)alloc(64 * 4);
  int* deg = (int*)alloc((size_t)N * 4);
  int* offs = (int*)alloc((size_t)N * 4);
  int* cnt = (int*)alloc((size_t)N * 4);
  int* sorted = (int*)alloc((size_t)E * 4);
  int* dd = (int*)alloc((size_t)Epad * 4);
  int* dsr = (int*)alloc((size_t)Epad * 4);
  short* es = (short*)alloc((size_t)Epad * 2);
  short* Wt1 = (short*)alloc((size_t)L * 64 * 160 * 2);
  short* Wt2 = (short*)alloc((size_t)L * 64 * 64 * 2);
  short* Wt1s = (short*)alloc((size_t)64 * 160 * 2);
  short* Wt2s = (short*)alloc((size_t)64 * 64 * 2);

  const int B = 256;
  const size_t REG = (size_t)NSH * 128;
  int gridE256 = (E + 255) / 256;
  int gridEb = Epad / 128;
  int gridM64 = (N + 63) / 64;
  int gridN64 = (N * 64 + B - 1) / B;
  int gridN = (N + B - 1) / B;

  // setup
  hipMemsetAsync(deg, 0, (size_t)N * 4, stream);
  hipMemsetAsync(cnt, 0, (size_t)N * 4, stream);
  lin_in_kernel<<<gridN64, B, 0, stream>>>(x, lin_W, lin_b, h, hb, N);
  deg_kernel<<<gridE256, B, 0, stream>>>(ei, deg, E);
  scan_kernel<<<1, 1024, 0, stream>>>(deg, offs, N);
  fill_kernel<<<gridE256, B, 0, stream>>>(ei, offs, cnt, sorted, E);
  gather_edges_kernel<<<(Epad + 255) / 256, B, 0, stream>>>(ei, sorted, ea, dd,
                                                            dsr, es, E, Epad);
  pack_w1_kernel<<<(L * 64 * 160 + 255) / 256, B, 0, stream>>>(msg_W1, Wt1, L);
  pack_w2_kernel<<<(L * 64 * 64 + 255) / 256, B, 0, stream>>>(msg_W2, Wt2, L);

  for (int l = 0; l < L; ++l) {
    const short* Wt1l = Wt1 + (size_t)l * 64 * 160;
    const short* Wt2l = Wt2 + (size_t)l * 64 * 64;
    const float* U1 = upd_W1 + (size_t)l * 128 * 64;
    const float* U2 = upd_W2 + (size_t)l * 64 * 64;
    hipMemsetAsync(stats, 0, (size_t)4 * REG * 4, stream);
    hipMemsetAsync(aggr, 0, (size_t)N * 64 * 4, stream);
    edge_pass_a<<<gridEb, 256, 0, stream>>>(hb, Wt1l, msg_b1 + l * 64, dd, dsr,
                                            es, stats, E);
    bn_finalize_pack1<<<(64 * 160 + 255) / 256, B, 0, stream>>>(
        stats, msg_g1 + l * 64, msg_be1 + l * 64, (float)E,
        msg_W1 + (size_t)l * 129 * 64, msg_b1 + l * 64, Wt1s, b1s);
    edge_pass_b<<<gridEb, 256, 0, stream>>>(hb, Wt1s, b1s, dd, dsr, es, Wt2l,
                                            msg_b2 + l * 64, stats + REG, E);
    bn_finalize_pack2<<<(64 * 64 + 255) / 256, B, 0, stream>>>(
        stats + REG, msg_g2 + l * 64, msg_be2 + l * 64, (float)E,
        msg_W2 + (size_t)l * 64 * 64, msg_b2 + l * 64, Wt2s, b2s);
    edge_pass_c<<<gridEb, 256, 0, stream>>>(hb, Wt1s, b1s, dd, dsr, es, Wt2s,
                                            b2s, aggr, E);
    node_gemm1_v3<<<gridM64, 256, 0, stream>>>(h, aggr, U1, upd_b1 + l * 64,
                                               u1, stats + 2 * REG, N);
    bn_finalize_kernel<<<1, 64, 0, stream>>>(stats + 2 * REG, upd_g1 + l * 64,
                                             upd_be1 + l * 64, (float)N, acu1);
    node_gemm2_v3<<<gridM64, 256, 0, stream>>>(u1, acu1, U2, upd_b2 + l * 64,
                                               u2, stats + 3 * REG, N);
    bn_finalize_kernel<<<1, 64, 0, stream>>>(stats + 3 * REG, upd_g2 + l * 64,
                                             upd_be2 + l * 64, (float)N, acu2);
    residual_kernel<<<gridN64, B, 0, stream>>>(h, hb, u2, acu2, N * 64);
  }
  pred_kernel<<<gridN, B, 0, stream>>>(h, pred_W, pred_b, out, N);
}